// Round 8
// baseline (326.762 us; speedup 1.0000x reference)
//
#include <hip/hip_runtime.h>
#include <hip/hip_bf16.h>

// 2-layer GCN (PyG GCNConv) on MI355X.
// R8: op-count cuts in both agg kernels (R7 was neutral: moved ops LDS->DS
// pipe without reducing them).
//   - agg1f dot: lane computes 4 partial outputs from its OWN 8 feats
//     (32 fma, 0 shfl) + 12-shfl fp-reduce; W2 slice = 8 float4 loads;
//     store = 8 x uint2 (was 32 shfl + 32 dword loads + 32 x 2B stores).
//   - agg2: uint2 gather (8 lanes/row): reduce 32->12 shfl, same 16 edges
//     in flight.
//   - rowptr2 (beg,end) uint2 single load; per-node invariant loads hoisted
//     above the gather loop.

#define IN_DIM 128
#define HID_DIM 64
#define OUT_DIM 32
#define BSHIFT 8
#define BSIZE 256
#define BMASK 255
#define PEB 8192   // edges per partition block

__device__ inline unsigned pack_bf16x2(float a, float b) {
    unsigned ua = __float_as_uint(a), ub = __float_as_uint(b);
    unsigned ra = (ua + 0x7fffu + ((ua >> 16) & 1u)) >> 16;        // RNE
    unsigned rb = (ub + 0x7fffu + ((ub >> 16) & 1u)) & 0xffff0000u;
    return (ra & 0xffffu) | rb;
}
#define BF_LO(w) __uint_as_float((w) << 16)
#define BF_HI(w) __uint_as_float((w) & 0xffff0000u)

#define ACC8(q)                                         \
    do {                                                \
        acc[0] += BF_LO((q).x); acc[1] += BF_HI((q).x); \
        acc[2] += BF_LO((q).y); acc[3] += BF_HI((q).y); \
        acc[4] += BF_LO((q).z); acc[5] += BF_HI((q).z); \
        acc[6] += BF_LO((q).w); acc[7] += BF_HI((q).w); \
    } while (0)

#define ACC4(q)                                         \
    do {                                                \
        acc[0] += BF_LO((q).x); acc[1] += BF_HI((q).x); \
        acc[2] += BF_LO((q).y); acc[3] += BF_HI((q).y); \
    } while (0)

// ---------------------------------------------------------------- pass 1: bucket histogram
__global__ __launch_bounds__(256) void k_hist(const int* __restrict__ dst, int E,
                                              int* __restrict__ mat, int B, int nPB) {
    __shared__ int cnt[512];
    int t = threadIdx.x;
    for (int b = t; b < B; b += 256) cnt[b] = 0;
    __syncthreads();
    int base = blockIdx.x * PEB;
#pragma unroll
    for (int i = 0; i < PEB / 256; ++i) {
        int e = base + i * 256 + t;
        if (e < E) atomicAdd(&cnt[dst[e] >> BSHIFT], 1);
    }
    __syncthreads();
    for (int b = t; b < B; b += 256) mat[b * nPB + blockIdx.x] = cnt[b];
}

// ---------------------------------------------------------------- scan (2-level)
__global__ void k_chunk_sums(const int* __restrict__ arr, int M, int* __restrict__ sums) {
    __shared__ int sdata[256];
    int t = threadIdx.x;
    int base = blockIdx.x * 1024 + t * 4;
    int s = 0;
#pragma unroll
    for (int i = 0; i < 4; ++i) {
        int idx = base + i;
        if (idx < M) s += arr[idx];
    }
    sdata[t] = s;
    __syncthreads();
    for (int off = 128; off > 0; off >>= 1) {
        if (t < off) sdata[t] += sdata[t + off];
        __syncthreads();
    }
    if (t == 0) sums[blockIdx.x] = sdata[0];
}

__global__ void k_scan_sums(int* __restrict__ sums, int nchunks) {
    __shared__ int buf[1024];
    int t = threadIdx.x;  // 1024 threads
    int v = (t < nchunks) ? sums[t] : 0;
    buf[t] = v;
    __syncthreads();
    for (int off = 1; off < 1024; off <<= 1) {
        int x = (t >= off) ? buf[t - off] : 0;
        __syncthreads();
        buf[t] += x;
        __syncthreads();
    }
    if (t < nchunks) sums[t] = buf[t] - v;  // exclusive
}

__global__ void k_scan_chunks(const int* __restrict__ arr, int M,
                              const int* __restrict__ sums, int* __restrict__ out) {
    __shared__ int tsum[256];
    int t = threadIdx.x;
    int idx0 = blockIdx.x * 1024 + t * 4;
    int v[4];
    int s = 0;
#pragma unroll
    for (int i = 0; i < 4; ++i) {
        int idx = idx0 + i;
        v[i] = (idx < M) ? arr[idx] : 0;
        s += v[i];
    }
    tsum[t] = s;
    __syncthreads();
    int mine = s;
    for (int off = 1; off < 256; off <<= 1) {
        int x = (t >= off) ? tsum[t - off] : 0;
        __syncthreads();
        tsum[t] += x;
        __syncthreads();
    }
    int run = tsum[t] - mine + sums[blockIdx.x];
#pragma unroll
    for (int i = 0; i < 4; ++i) {
        int idx = idx0 + i;
        if (idx < M) out[idx] = run;
        run += v[i];
    }
}

// ---------------------------------------------------------------- pass 2: partition
__global__ __launch_bounds__(256) void k_partition(const int* __restrict__ src,
                                                   const int* __restrict__ dst, int E,
                                                   const int* __restrict__ mats,
                                                   unsigned* __restrict__ packed,
                                                   int B, int nPB) {
    __shared__ int off[512];
    int t = threadIdx.x;
    for (int b = t; b < B; b += 256) off[b] = mats[b * nPB + blockIdx.x];
    __syncthreads();
    int base = blockIdx.x * PEB;
#pragma unroll
    for (int i = 0; i < PEB / 256; ++i) {
        int e = base + i * 256 + t;
        if (e < E) {
            int d = dst[e];
            int s = src[e];
            int slot = atomicAdd(&off[d >> BSHIFT], 1);
            packed[slot] = ((unsigned)s << BSHIFT) | (unsigned)(d & BMASK);
        }
    }
}

// ---------------------------------------------------------------- pass 3: per-bucket CSR build
__global__ __launch_bounds__(256) void k_csrfill(const unsigned* __restrict__ packed,
                                                 const int* __restrict__ mats,
                                                 int* __restrict__ colidx,
                                                 uint2* __restrict__ rowptr2,
                                                 float* __restrict__ dinv,
                                                 int N, int E, int B, int nPB) {
    __shared__ int ldeg[256];
    __shared__ int lscan[256];
    __shared__ int sexc[256];
    __shared__ int lfill[256];
    int t = threadIdx.x, bkt = blockIdx.x;
    int base = mats[bkt * nPB];
    int end  = (bkt + 1 < B) ? mats[(bkt + 1) * nPB] : E;
    ldeg[t] = 0;
    __syncthreads();
    for (int e = base + t; e < end; e += 256)
        atomicAdd(&ldeg[packed[e] & BMASK], 1);
    __syncthreads();
    int v = ldeg[t];
    lscan[t] = v;
    __syncthreads();
    for (int off = 1; off < 256; off <<= 1) {
        int x = (t >= off) ? lscan[t - off] : 0;
        __syncthreads();
        lscan[t] += x;
        __syncthreads();
    }
    int exc = lscan[t] - v;
    sexc[t] = exc;
    lfill[t] = 0;
    int node = (bkt << BSHIFT) + t;
    if (node < N) {
        rowptr2[node] = make_uint2((unsigned)(base + exc), (unsigned)(base + exc + v));
        dinv[node] = rsqrtf((float)v + 1.0f);
    }
    __syncthreads();
    for (int e = base + t; e < end; e += 256) {
        unsigned w = packed[e];
        int ld = w & BMASK;
        int pos = base + sexc[ld] + atomicAdd(&lfill[ld], 1);
        colidx[pos] = (int)(w >> BSHIFT);
    }
}

// ---------------------------------------------------------------- GEMM1: g1b = bf16((x @ W1) * dinv)
__global__ __launch_bounds__(256) void k_gemm1(const float* __restrict__ x,
                                               const float* __restrict__ W,
                                               const float* __restrict__ dinv,
                                               unsigned* __restrict__ g1b, int N) {
    __shared__ float xs[64 * 128];
    __shared__ float ws[128 * 64];
    int t = threadIdx.x;
    int row0 = blockIdx.x * 64;

    const float4* W4 = (const float4*)W;
    float4* ws4 = (float4*)ws;
#pragma unroll
    for (int i = 0; i < 8; ++i) ws4[t + 256 * i] = W4[t + 256 * i];
#pragma unroll
    for (int i = 0; i < 8; ++i) {
        int l = t + 256 * i;
        int r = l >> 5;
        int c4 = l & 31;
        int row = row0 + r;
        float4 val = make_float4(0.f, 0.f, 0.f, 0.f);
        if (row < N) val = ((const float4*)(x + (size_t)row * IN_DIM))[c4];
        *(float4*)&xs[r * IN_DIM + c4 * 4] = val;
    }
    __syncthreads();

    int tx = t & 15;
    int ty = t >> 4;
    float acc[4][4] = {};
    for (int k = 0; k < 128; k += 4) {
        float a[4][4], b[4][4];
#pragma unroll
        for (int i = 0; i < 4; ++i)
            *(float4*)a[i] = *(const float4*)&xs[(ty * 4 + i) * IN_DIM + k];
#pragma unroll
        for (int kk = 0; kk < 4; ++kk)
            *(float4*)b[kk] = *(const float4*)&ws[(k + kk) * HID_DIM + tx * 4];
#pragma unroll
        for (int i = 0; i < 4; ++i)
#pragma unroll
            for (int kk = 0; kk < 4; ++kk)
#pragma unroll
                for (int j = 0; j < 4; ++j)
                    acc[i][j] += a[i][kk] * b[kk][j];
    }
#pragma unroll
    for (int i = 0; i < 4; ++i) {
        int row = row0 + ty * 4 + i;
        if (row < N) {
            float dv = dinv[row];
            uint2 u;
            u.x = pack_bf16x2(acc[i][0] * dv, acc[i][1] * dv);
            u.y = pack_bf16x2(acc[i][2] * dv, acc[i][3] * dv);
            *(uint2*)&g1b[(size_t)row * 32 + tx * 2] = u;
        }
    }
}

// ---------------------------------------------------------------- agg1 + fused GEMM2
// One wave per node, NO LDS, NO barriers.
// Gather: lane = (grp 0..7, fp 0..7); lane loads uint4 = 16B, 8 lanes/row ->
// 8 edges per load inst, 16 edges in flight.
// Epilogue: 3-level grp-reduce (24 shfl) -> relu on all lanes -> lane
// computes 4 partial outputs j=grp*4+c from its own 8 feats (32 fma) ->
// 3-level fp-reduce (12 shfl) -> fp==0 lanes store uint2 (8B).
// W2 slice (8 float4), self-loop row, dinv, bias all loaded BEFORE the
// gather loop so they ride under the gather's vmcnt window.
__global__ __launch_bounds__(256) void k_agg1f(const unsigned* __restrict__ g1,
                                               const uint2* __restrict__ rowptr2,
                                               const int* __restrict__ colidx,
                                               const float* __restrict__ dinv,
                                               const float* __restrict__ b1,
                                               const float* __restrict__ W2,
                                               unsigned short* __restrict__ g2b, int N) {
    int t = threadIdx.x;
    int dd = (blockIdx.x * 256 + t) >> 6;
    bool live = dd < N;
    int d = live ? dd : N - 1;
    int lane = t & 63, grp = lane >> 3, fp = lane & 7;

    // hoisted invariant loads
    uint2 be = rowptr2[d];
    float dv = dinv[d];
    uint4 sq = *(const uint4*)&g1[(size_t)d * 32 + fp * 4];
    float4 bb0 = ((const float4*)b1)[fp * 2];
    float4 bb1 = ((const float4*)b1)[fp * 2 + 1];
    float4 w2r[8];  // w2r[i] = W2[(fp*8+i)][grp*4 .. +3]
#pragma unroll
    for (int i = 0; i < 8; ++i)
        w2r[i] = *(const float4*)&W2[(size_t)(fp * 8 + i) * OUT_DIM + grp * 4];

    float acc[8] = {};
    int e = (int)be.x, end = (int)be.y;
    for (; e + 16 <= end; e += 16) {
        int s0 = colidx[e + grp];
        int s1 = colidx[e + 8 + grp];
        uint4 q0 = *(const uint4*)&g1[(size_t)s0 * 32 + fp * 4];
        uint4 q1 = *(const uint4*)&g1[(size_t)s1 * 32 + fp * 4];
        ACC8(q0);
        ACC8(q1);
    }
    for (; e + 8 <= end; e += 8) {
        int s = colidx[e + grp];
        uint4 q = *(const uint4*)&g1[(size_t)s * 32 + fp * 4];
        ACC8(q);
    }
    if (e < end) {  // 1..7 edges left
        int cnt = end - e;
        int s = colidx[(grp < cnt) ? e + grp : e];
        uint4 q = *(const uint4*)&g1[(size_t)s * 32 + fp * 4];
        if (grp < cnt) ACC8(q);
    }
#pragma unroll
    for (int i = 0; i < 8; ++i) {
        acc[i] += __shfl_xor(acc[i], 8);
        acc[i] += __shfl_xor(acc[i], 16);
        acc[i] += __shfl_xor(acc[i], 32);
    }

    // self-loop + scale + bias + relu, on ALL lanes (row replicated 8x over grp)
    ACC8(sq);
    acc[0] = fmaxf(dv * acc[0] + bb0.x, 0.f);
    acc[1] = fmaxf(dv * acc[1] + bb0.y, 0.f);
    acc[2] = fmaxf(dv * acc[2] + bb0.z, 0.f);
    acc[3] = fmaxf(dv * acc[3] + bb0.w, 0.f);
    acc[4] = fmaxf(dv * acc[4] + bb1.x, 0.f);
    acc[5] = fmaxf(dv * acc[5] + bb1.y, 0.f);
    acc[6] = fmaxf(dv * acc[6] + bb1.z, 0.f);
    acc[7] = fmaxf(dv * acc[7] + bb1.w, 0.f);

    // fused GEMM2: lane (grp,fp) -> partials for outputs j = grp*4+c over
    // feats fp*8..fp*8+7; fp-reduce completes the k-sum.
    float p0 = 0.f, p1 = 0.f, p2 = 0.f, p3 = 0.f;
#pragma unroll
    for (int i = 0; i < 8; ++i) {
        p0 += acc[i] * w2r[i].x;
        p1 += acc[i] * w2r[i].y;
        p2 += acc[i] * w2r[i].z;
        p3 += acc[i] * w2r[i].w;
    }
    p0 += __shfl_xor(p0, 1); p0 += __shfl_xor(p0, 2); p0 += __shfl_xor(p0, 4);
    p1 += __shfl_xor(p1, 1); p1 += __shfl_xor(p1, 2); p1 += __shfl_xor(p1, 4);
    p2 += __shfl_xor(p2, 1); p2 += __shfl_xor(p2, 2); p2 += __shfl_xor(p2, 4);
    p3 += __shfl_xor(p3, 1); p3 += __shfl_xor(p3, 2); p3 += __shfl_xor(p3, 4);
    if (live && fp == 0) {
        uint2 u;
        u.x = pack_bf16x2(p0 * dv, p1 * dv);
        u.y = pack_bf16x2(p2 * dv, p3 * dv);
        *(uint2*)&g2b[(size_t)dd * 32 + grp * 4] = u;
    }
}

// ---------------------------------------------------------------- agg layer 2
// One wave per node. lane = (grp 0..7, fp 0..7); lane loads uint2 = 8B,
// 8 lanes cover one 64B row -> 8 edges per load inst, 16 in flight.
// Reduce: 3 levels x 4 accs = 12 shfl. fp holds feats fp*4..fp*4+3.
__global__ __launch_bounds__(256) void k_agg2(const unsigned* __restrict__ g2,
                                              const uint2* __restrict__ rowptr2,
                                              const int* __restrict__ colidx,
                                              const float* __restrict__ dinv,
                                              const float* __restrict__ b2,
                                              float* __restrict__ out, int N) {
    int t = threadIdx.x;
    int dd = (blockIdx.x * 256 + t) >> 6;
    bool live = dd < N;
    int d = live ? dd : N - 1;
    int lane = t & 63, grp = lane >> 3, fp = lane & 7;

    // hoisted invariant loads
    uint2 be = rowptr2[d];
    float dv = dinv[d];
    uint2 sq = *(const uint2*)&g2[(size_t)d * 16 + fp * 2];
    float4 bb = ((const float4*)b2)[fp];

    float acc[4] = {};
    int e = (int)be.x, end = (int)be.y;
    for (; e + 16 <= end; e += 16) {
        int s0 = colidx[e + grp];
        int s1 = colidx[e + 8 + grp];
        uint2 q0 = *(const uint2*)&g2[(size_t)s0 * 16 + fp * 2];
        uint2 q1 = *(const uint2*)&g2[(size_t)s1 * 16 + fp * 2];
        ACC4(q0);
        ACC4(q1);
    }
    for (; e + 8 <= end; e += 8) {
        int s = colidx[e + grp];
        uint2 q = *(const uint2*)&g2[(size_t)s * 16 + fp * 2];
        ACC4(q);
    }
    if (e < end) {  // 1..7 edges left
        int cnt = end - e;
        int s = colidx[(grp < cnt) ? e + grp : e];
        uint2 q = *(const uint2*)&g2[(size_t)s * 16 + fp * 2];
        if (grp < cnt) ACC4(q);
    }
#pragma unroll
    for (int i = 0; i < 4; ++i) {
        acc[i] += __shfl_xor(acc[i], 8);
        acc[i] += __shfl_xor(acc[i], 16);
        acc[i] += __shfl_xor(acc[i], 32);
    }
    // self-loop + epilogue
    ACC4(sq);
    if (live && grp == 0) {
        float4 r;
        r.x = dv * acc[0] + bb.x;
        r.y = dv * acc[1] + bb.y;
        r.z = dv * acc[2] + bb.z;
        r.w = dv * acc[3] + bb.w;
        *(float4*)&out[(size_t)dd * OUT_DIM + fp * 4] = r;
    }
}

// ---------------------------------------------------------------- launch
extern "C" void kernel_launch(void* const* d_in, const int* in_sizes, int n_in,
                              void* d_out, int out_size, void* d_ws, size_t ws_size,
                              hipStream_t stream) {
    const float* x  = (const float*)d_in[0];
    const int*   ei = (const int*)d_in[1];
    const float* W1 = (const float*)d_in[2];
    const float* b1 = (const float*)d_in[3];
    const float* W2 = (const float*)d_in[4];
    const float* b2 = (const float*)d_in[5];
    float* out = (float*)d_out;

    const int N = in_sizes[0] / IN_DIM;
    const int E = in_sizes[1] / 2;
    const int* src = ei;
    const int* dst = ei + E;

    const int B   = (N + BSIZE - 1) / BSIZE;
    const int nPB = (E + PEB - 1) / PEB;
    const int M   = B * nPB;
    const int nchunks = (M + 1023) / 1024;

    char* p = (char*)d_ws;
    auto alloc = [&](size_t bytes) -> void* {
        void* r = (void*)p;
        p += (bytes + 255) & ~(size_t)255;
        return r;
    };
    int*            mat     = (int*)alloc((size_t)M * 4);
    int*            mats    = (int*)alloc((size_t)M * 4);
    int*            sums    = (int*)alloc((size_t)nchunks * 4);
    unsigned*       packed  = (unsigned*)alloc((size_t)E * 4);
    int*            colidx  = (int*)alloc((size_t)E * 4);
    uint2*          rowptr2 = (uint2*)alloc((size_t)N * 8);
    float*          dinv    = (float*)alloc((size_t)N * 4);
    unsigned*       g1b     = (unsigned*)alloc((size_t)N * 32 * 4);       // bf16x2 x 32/row
    unsigned short* g2b     = (unsigned short*)alloc((size_t)N * 32 * 2); // bf16 x 32/row

    k_hist<<<nPB, 256, 0, stream>>>(dst, E, mat, B, nPB);
    k_chunk_sums<<<nchunks, 256, 0, stream>>>(mat, M, sums);
    k_scan_sums<<<1, 1024, 0, stream>>>(sums, nchunks);
    k_scan_chunks<<<nchunks, 256, 0, stream>>>(mat, M, sums, mats);
    k_partition<<<nPB, 256, 0, stream>>>(src, dst, E, mats, packed, B, nPB);
    k_csrfill<<<B, 256, 0, stream>>>(packed, mats, colidx, rowptr2, dinv, N, E, B, nPB);

    k_gemm1<<<(N + 63) / 64, 256, 0, stream>>>(x, W1, dinv, g1b, N);
    k_agg1f<<<(N + 3) / 4, 256, 0, stream>>>(g1b, rowptr2, colidx, dinv, b1, W2,
                                             g2b, N);
    k_agg2<<<(N + 3) / 4, 256, 0, stream>>>((const unsigned*)g2b, rowptr2, colidx,
                                            dinv, b2, out, N);
}

// Round 9
// 292.542 us; speedup vs baseline: 1.1170x; 1.1170x over previous
//
#include <hip/hip_runtime.h>
#include <hip/hip_bf16.h>

// 2-layer GCN (PyG GCNConv) on MI355X.
// R9: DE-fuse GEMM2 from agg1. Evidence: unfused agg1 (R4) = 54.6us vs every
// fused variant ~71.5us (R6/R7) and the R8 hoist regression (126us) showed
// the gather loop is fragile to added register pressure. New split:
//   k_agg1: R7's exact uint4 gather + minimal epilogue -> t1b (bf16, 128B/row)
//   k_gemm2b: LDS-tiled 64-node GEMM (t1b @ W2)*dinv -> g2b (bf16)
// Keep: rowptr2 (uint2 single load), R8's uint2-gather agg2.

#define IN_DIM 128
#define HID_DIM 64
#define OUT_DIM 32
#define BSHIFT 8
#define BSIZE 256
#define BMASK 255
#define PEB 8192   // edges per partition block

__device__ inline unsigned pack_bf16x2(float a, float b) {
    unsigned ua = __float_as_uint(a), ub = __float_as_uint(b);
    unsigned ra = (ua + 0x7fffu + ((ua >> 16) & 1u)) >> 16;        // RNE
    unsigned rb = (ub + 0x7fffu + ((ub >> 16) & 1u)) & 0xffff0000u;
    return (ra & 0xffffu) | rb;
}
#define BF_LO(w) __uint_as_float((w) << 16)
#define BF_HI(w) __uint_as_float((w) & 0xffff0000u)

#define ACC8(q)                                         \
    do {                                                \
        acc[0] += BF_LO((q).x); acc[1] += BF_HI((q).x); \
        acc[2] += BF_LO((q).y); acc[3] += BF_HI((q).y); \
        acc[4] += BF_LO((q).z); acc[5] += BF_HI((q).z); \
        acc[6] += BF_LO((q).w); acc[7] += BF_HI((q).w); \
    } while (0)

#define ACC4(q)                                         \
    do {                                                \
        acc[0] += BF_LO((q).x); acc[1] += BF_HI((q).x); \
        acc[2] += BF_LO((q).y); acc[3] += BF_HI((q).y); \
    } while (0)

// ---------------------------------------------------------------- pass 1: bucket histogram
__global__ __launch_bounds__(256) void k_hist(const int* __restrict__ dst, int E,
                                              int* __restrict__ mat, int B, int nPB) {
    __shared__ int cnt[512];
    int t = threadIdx.x;
    for (int b = t; b < B; b += 256) cnt[b] = 0;
    __syncthreads();
    int base = blockIdx.x * PEB;
#pragma unroll
    for (int i = 0; i < PEB / 256; ++i) {
        int e = base + i * 256 + t;
        if (e < E) atomicAdd(&cnt[dst[e] >> BSHIFT], 1);
    }
    __syncthreads();
    for (int b = t; b < B; b += 256) mat[b * nPB + blockIdx.x] = cnt[b];
}

// ---------------------------------------------------------------- scan (2-level)
__global__ void k_chunk_sums(const int* __restrict__ arr, int M, int* __restrict__ sums) {
    __shared__ int sdata[256];
    int t = threadIdx.x;
    int base = blockIdx.x * 1024 + t * 4;
    int s = 0;
#pragma unroll
    for (int i = 0; i < 4; ++i) {
        int idx = base + i;
        if (idx < M) s += arr[idx];
    }
    sdata[t] = s;
    __syncthreads();
    for (int off = 128; off > 0; off >>= 1) {
        if (t < off) sdata[t] += sdata[t + off];
        __syncthreads();
    }
    if (t == 0) sums[blockIdx.x] = sdata[0];
}

__global__ void k_scan_sums(int* __restrict__ sums, int nchunks) {
    __shared__ int buf[1024];
    int t = threadIdx.x;  // 1024 threads
    int v = (t < nchunks) ? sums[t] : 0;
    buf[t] = v;
    __syncthreads();
    for (int off = 1; off < 1024; off <<= 1) {
        int x = (t >= off) ? buf[t - off] : 0;
        __syncthreads();
        buf[t] += x;
        __syncthreads();
    }
    if (t < nchunks) sums[t] = buf[t] - v;  // exclusive
}

__global__ void k_scan_chunks(const int* __restrict__ arr, int M,
                              const int* __restrict__ sums, int* __restrict__ out) {
    __shared__ int tsum[256];
    int t = threadIdx.x;
    int idx0 = blockIdx.x * 1024 + t * 4;
    int v[4];
    int s = 0;
#pragma unroll
    for (int i = 0; i < 4; ++i) {
        int idx = idx0 + i;
        v[i] = (idx < M) ? arr[idx] : 0;
        s += v[i];
    }
    tsum[t] = s;
    __syncthreads();
    int mine = s;
    for (int off = 1; off < 256; off <<= 1) {
        int x = (t >= off) ? tsum[t - off] : 0;
        __syncthreads();
        tsum[t] += x;
        __syncthreads();
    }
    int run = tsum[t] - mine + sums[blockIdx.x];
#pragma unroll
    for (int i = 0; i < 4; ++i) {
        int idx = idx0 + i;
        if (idx < M) out[idx] = run;
        run += v[i];
    }
}

// ---------------------------------------------------------------- pass 2: partition
__global__ __launch_bounds__(256) void k_partition(const int* __restrict__ src,
                                                   const int* __restrict__ dst, int E,
                                                   const int* __restrict__ mats,
                                                   unsigned* __restrict__ packed,
                                                   int B, int nPB) {
    __shared__ int off[512];
    int t = threadIdx.x;
    for (int b = t; b < B; b += 256) off[b] = mats[b * nPB + blockIdx.x];
    __syncthreads();
    int base = blockIdx.x * PEB;
#pragma unroll
    for (int i = 0; i < PEB / 256; ++i) {
        int e = base + i * 256 + t;
        if (e < E) {
            int d = dst[e];
            int s = src[e];
            int slot = atomicAdd(&off[d >> BSHIFT], 1);
            packed[slot] = ((unsigned)s << BSHIFT) | (unsigned)(d & BMASK);
        }
    }
}

// ---------------------------------------------------------------- pass 3: per-bucket CSR build
__global__ __launch_bounds__(256) void k_csrfill(const unsigned* __restrict__ packed,
                                                 const int* __restrict__ mats,
                                                 int* __restrict__ colidx,
                                                 uint2* __restrict__ rowptr2,
                                                 float* __restrict__ dinv,
                                                 int N, int E, int B, int nPB) {
    __shared__ int ldeg[256];
    __shared__ int lscan[256];
    __shared__ int sexc[256];
    __shared__ int lfill[256];
    int t = threadIdx.x, bkt = blockIdx.x;
    int base = mats[bkt * nPB];
    int end  = (bkt + 1 < B) ? mats[(bkt + 1) * nPB] : E;
    ldeg[t] = 0;
    __syncthreads();
    for (int e = base + t; e < end; e += 256)
        atomicAdd(&ldeg[packed[e] & BMASK], 1);
    __syncthreads();
    int v = ldeg[t];
    lscan[t] = v;
    __syncthreads();
    for (int off = 1; off < 256; off <<= 1) {
        int x = (t >= off) ? lscan[t - off] : 0;
        __syncthreads();
        lscan[t] += x;
        __syncthreads();
    }
    int exc = lscan[t] - v;
    sexc[t] = exc;
    lfill[t] = 0;
    int node = (bkt << BSHIFT) + t;
    if (node < N) {
        rowptr2[node] = make_uint2((unsigned)(base + exc), (unsigned)(base + exc + v));
        dinv[node] = rsqrtf((float)v + 1.0f);
    }
    __syncthreads();
    for (int e = base + t; e < end; e += 256) {
        unsigned w = packed[e];
        int ld = w & BMASK;
        int pos = base + sexc[ld] + atomicAdd(&lfill[ld], 1);
        colidx[pos] = (int)(w >> BSHIFT);
    }
}

// ---------------------------------------------------------------- GEMM1: g1b = bf16((x @ W1) * dinv)
__global__ __launch_bounds__(256) void k_gemm1(const float* __restrict__ x,
                                               const float* __restrict__ W,
                                               const float* __restrict__ dinv,
                                               unsigned* __restrict__ g1b, int N) {
    __shared__ float xs[64 * 128];
    __shared__ float ws[128 * 64];
    int t = threadIdx.x;
    int row0 = blockIdx.x * 64;

    const float4* W4 = (const float4*)W;
    float4* ws4 = (float4*)ws;
#pragma unroll
    for (int i = 0; i < 8; ++i) ws4[t + 256 * i] = W4[t + 256 * i];
#pragma unroll
    for (int i = 0; i < 8; ++i) {
        int l = t + 256 * i;
        int r = l >> 5;
        int c4 = l & 31;
        int row = row0 + r;
        float4 val = make_float4(0.f, 0.f, 0.f, 0.f);
        if (row < N) val = ((const float4*)(x + (size_t)row * IN_DIM))[c4];
        *(float4*)&xs[r * IN_DIM + c4 * 4] = val;
    }
    __syncthreads();

    int tx = t & 15;
    int ty = t >> 4;
    float acc[4][4] = {};
    for (int k = 0; k < 128; k += 4) {
        float a[4][4], b[4][4];
#pragma unroll
        for (int i = 0; i < 4; ++i)
            *(float4*)a[i] = *(const float4*)&xs[(ty * 4 + i) * IN_DIM + k];
#pragma unroll
        for (int kk = 0; kk < 4; ++kk)
            *(float4*)b[kk] = *(const float4*)&ws[(k + kk) * HID_DIM + tx * 4];
#pragma unroll
        for (int i = 0; i < 4; ++i)
#pragma unroll
            for (int kk = 0; kk < 4; ++kk)
#pragma unroll
                for (int j = 0; j < 4; ++j)
                    acc[i][j] += a[i][kk] * b[kk][j];
    }
#pragma unroll
    for (int i = 0; i < 4; ++i) {
        int row = row0 + ty * 4 + i;
        if (row < N) {
            float dv = dinv[row];
            uint2 u;
            u.x = pack_bf16x2(acc[i][0] * dv, acc[i][1] * dv);
            u.y = pack_bf16x2(acc[i][2] * dv, acc[i][3] * dv);
            *(uint2*)&g1b[(size_t)row * 32 + tx * 2] = u;
        }
    }
}

// ---------------------------------------------------------------- agg layer 1 (unfused)
// One wave per node. Gather: lane = (grp 0..7, fp 0..7); lane loads uint4 =
// 16B, 8 lanes/row -> 8 edges per load inst, 16 edges in flight (R7's exact
// loop — do NOT add live state across it; R8's hoists serialized the gather).
// Epilogue: 24-shfl reduce, self-loop, dinv/bias/relu, grp==0 lanes write
// t1b row as bf16 (8 x uint4 = 128B coalesced).
__global__ __launch_bounds__(256) void k_agg1(const unsigned* __restrict__ g1,
                                              const uint2* __restrict__ rowptr2,
                                              const int* __restrict__ colidx,
                                              const float* __restrict__ dinv,
                                              const float* __restrict__ b1,
                                              unsigned* __restrict__ t1b, int N) {
    int t = threadIdx.x;
    int dd = (blockIdx.x * 256 + t) >> 6;
    bool live = dd < N;
    int d = live ? dd : N - 1;
    int lane = t & 63, grp = lane >> 3, fp = lane & 7;

    uint2 be = rowptr2[d];
    float acc[8] = {};
    int e = (int)be.x, end = (int)be.y;
    for (; e + 16 <= end; e += 16) {
        int s0 = colidx[e + grp];
        int s1 = colidx[e + 8 + grp];
        uint4 q0 = *(const uint4*)&g1[(size_t)s0 * 32 + fp * 4];
        uint4 q1 = *(const uint4*)&g1[(size_t)s1 * 32 + fp * 4];
        ACC8(q0);
        ACC8(q1);
    }
    for (; e + 8 <= end; e += 8) {
        int s = colidx[e + grp];
        uint4 q = *(const uint4*)&g1[(size_t)s * 32 + fp * 4];
        ACC8(q);
    }
    if (e < end) {  // 1..7 edges left
        int cnt = end - e;
        int s = colidx[(grp < cnt) ? e + grp : e];
        uint4 q = *(const uint4*)&g1[(size_t)s * 32 + fp * 4];
        if (grp < cnt) ACC8(q);
    }
#pragma unroll
    for (int i = 0; i < 8; ++i) {
        acc[i] += __shfl_xor(acc[i], 8);
        acc[i] += __shfl_xor(acc[i], 16);
        acc[i] += __shfl_xor(acc[i], 32);
    }

    // self-loop + scale + bias + relu
    uint4 sq = *(const uint4*)&g1[(size_t)d * 32 + fp * 4];
    ACC8(sq);
    float dv = dinv[d];
    float4 bb0 = ((const float4*)b1)[fp * 2];
    float4 bb1 = ((const float4*)b1)[fp * 2 + 1];
    float v0 = fmaxf(dv * acc[0] + bb0.x, 0.f);
    float v1 = fmaxf(dv * acc[1] + bb0.y, 0.f);
    float v2 = fmaxf(dv * acc[2] + bb0.z, 0.f);
    float v3 = fmaxf(dv * acc[3] + bb0.w, 0.f);
    float v4 = fmaxf(dv * acc[4] + bb1.x, 0.f);
    float v5 = fmaxf(dv * acc[5] + bb1.y, 0.f);
    float v6 = fmaxf(dv * acc[6] + bb1.z, 0.f);
    float v7 = fmaxf(dv * acc[7] + bb1.w, 0.f);
    if (live && grp == 0) {
        uint4 u;
        u.x = pack_bf16x2(v0, v1);
        u.y = pack_bf16x2(v2, v3);
        u.z = pack_bf16x2(v4, v5);
        u.w = pack_bf16x2(v6, v7);
        *(uint4*)&t1b[(size_t)dd * 32 + fp * 4] = u;
    }
}

// ---------------------------------------------------------------- GEMM2: g2b = bf16((t1b @ W2) * dinv)
// 64 nodes/block, 256 threads. LDS: t1s (stride 33 uints -> bank-spread) +
// W2s 8KB. Thread (r = t>>2, q = t&3) computes outputs j in [8q, 8q+8).
__global__ __launch_bounds__(256) void k_gemm2b(const unsigned* __restrict__ t1b,
                                                const float* __restrict__ W2,
                                                const float* __restrict__ dinv,
                                                unsigned* __restrict__ g2b, int N) {
    __shared__ unsigned t1s[64 * 33];       // bf16x2, row stride 33 (+1 pad)
    __shared__ float W2s[HID_DIM * OUT_DIM];
    int t = threadIdx.x;
    int row0 = blockIdx.x * 64;

    const float4* W24 = (const float4*)W2;  // 512 float4
    float4* W2s4 = (float4*)W2s;
#pragma unroll
    for (int i = 0; i < 2; ++i) W2s4[t + 256 * i] = W24[t + 256 * i];
#pragma unroll
    for (int i = 0; i < 8; ++i) {           // 2048 uints
        int l = t + 256 * i;
        int r = l >> 5, c = l & 31;
        int row = row0 + r;
        unsigned val = 0;
        if (row < N) val = t1b[(size_t)row * 32 + c];
        t1s[r * 33 + c] = val;
    }
    __syncthreads();

    int r = t >> 2, q = t & 3;
    float acc[8] = {};
    const unsigned* trow = &t1s[r * 33];
    const float* wbase = &W2s[q * 8];
#pragma unroll
    for (int kp = 0; kp < 32; ++kp) {
        unsigned u = trow[kp];
        float a0 = BF_LO(u), a1 = BF_HI(u);
        float4 w00 = *(const float4*)&wbase[(2 * kp) * OUT_DIM];
        float4 w01 = *(const float4*)&wbase[(2 * kp) * OUT_DIM + 4];
        float4 w10 = *(const float4*)&wbase[(2 * kp + 1) * OUT_DIM];
        float4 w11 = *(const float4*)&wbase[(2 * kp + 1) * OUT_DIM + 4];
        acc[0] += a0 * w00.x + a1 * w10.x;
        acc[1] += a0 * w00.y + a1 * w10.y;
        acc[2] += a0 * w00.z + a1 * w10.z;
        acc[3] += a0 * w00.w + a1 * w10.w;
        acc[4] += a0 * w01.x + a1 * w11.x;
        acc[5] += a0 * w01.y + a1 * w11.y;
        acc[6] += a0 * w01.z + a1 * w11.z;
        acc[7] += a0 * w01.w + a1 * w11.w;
    }
    int row = row0 + r;
    if (row < N) {
        float dv = dinv[row];
        uint4 u;
        u.x = pack_bf16x2(acc[0] * dv, acc[1] * dv);
        u.y = pack_bf16x2(acc[2] * dv, acc[3] * dv);
        u.z = pack_bf16x2(acc[4] * dv, acc[5] * dv);
        u.w = pack_bf16x2(acc[6] * dv, acc[7] * dv);
        *(uint4*)&g2b[(size_t)row * 16 + q * 4] = u;
    }
}

// ---------------------------------------------------------------- agg layer 2
// One wave per node. lane = (grp 0..7, fp 0..7); lane loads uint2 = 8B,
// 8 lanes cover one 64B row -> 8 edges per load inst, 16 in flight.
__global__ __launch_bounds__(256) void k_agg2(const unsigned* __restrict__ g2,
                                              const uint2* __restrict__ rowptr2,
                                              const int* __restrict__ colidx,
                                              const float* __restrict__ dinv,
                                              const float* __restrict__ b2,
                                              float* __restrict__ out, int N) {
    int t = threadIdx.x;
    int dd = (blockIdx.x * 256 + t) >> 6;
    bool live = dd < N;
    int d = live ? dd : N - 1;
    int lane = t & 63, grp = lane >> 3, fp = lane & 7;

    uint2 be = rowptr2[d];
    float acc[4] = {};
    int e = (int)be.x, end = (int)be.y;
    for (; e + 16 <= end; e += 16) {
        int s0 = colidx[e + grp];
        int s1 = colidx[e + 8 + grp];
        uint2 q0 = *(const uint2*)&g2[(size_t)s0 * 16 + fp * 2];
        uint2 q1 = *(const uint2*)&g2[(size_t)s1 * 16 + fp * 2];
        ACC4(q0);
        ACC4(q1);
    }
    for (; e + 8 <= end; e += 8) {
        int s = colidx[e + grp];
        uint2 q = *(const uint2*)&g2[(size_t)s * 16 + fp * 2];
        ACC4(q);
    }
    if (e < end) {  // 1..7 edges left
        int cnt = end - e;
        int s = colidx[(grp < cnt) ? e + grp : e];
        uint2 q = *(const uint2*)&g2[(size_t)s * 16 + fp * 2];
        if (grp < cnt) ACC4(q);
    }
#pragma unroll
    for (int i = 0; i < 4; ++i) {
        acc[i] += __shfl_xor(acc[i], 8);
        acc[i] += __shfl_xor(acc[i], 16);
        acc[i] += __shfl_xor(acc[i], 32);
    }
    // self-loop + epilogue
    uint2 sq = *(const uint2*)&g2[(size_t)d * 16 + fp * 2];
    ACC4(sq);
    float dv = dinv[d];
    float4 bb = ((const float4*)b2)[fp];
    if (live && grp == 0) {
        float4 r;
        r.x = dv * acc[0] + bb.x;
        r.y = dv * acc[1] + bb.y;
        r.z = dv * acc[2] + bb.z;
        r.w = dv * acc[3] + bb.w;
        *(float4*)&out[(size_t)dd * OUT_DIM + fp * 4] = r;
    }
}

// ---------------------------------------------------------------- launch
extern "C" void kernel_launch(void* const* d_in, const int* in_sizes, int n_in,
                              void* d_out, int out_size, void* d_ws, size_t ws_size,
                              hipStream_t stream) {
    const float* x  = (const float*)d_in[0];
    const int*   ei = (const int*)d_in[1];
    const float* W1 = (const float*)d_in[2];
    const float* b1 = (const float*)d_in[3];
    const float* W2 = (const float*)d_in[4];
    const float* b2 = (const float*)d_in[5];
    float* out = (float*)d_out;

    const int N = in_sizes[0] / IN_DIM;
    const int E = in_sizes[1] / 2;
    const int* src = ei;
    const int* dst = ei + E;

    const int B   = (N + BSIZE - 1) / BSIZE;
    const int nPB = (E + PEB - 1) / PEB;
    const int M   = B * nPB;
    const int nchunks = (M + 1023) / 1024;

    char* p = (char*)d_ws;
    auto alloc = [&](size_t bytes) -> void* {
        void* r = (void*)p;
        p += (bytes + 255) & ~(size_t)255;
        return r;
    };
    int*      mat     = (int*)alloc((size_t)M * 4);
    int*      mats    = (int*)alloc((size_t)M * 4);
    int*      sums    = (int*)alloc((size_t)nchunks * 4);
    unsigned* packed  = (unsigned*)alloc((size_t)E * 4);
    int*      colidx  = (int*)alloc((size_t)E * 4);
    uint2*    rowptr2 = (uint2*)alloc((size_t)N * 8);
    float*    dinv    = (float*)alloc((size_t)N * 4);
    unsigned* g1b     = (unsigned*)alloc((size_t)N * 32 * 4);  // bf16x2 x 32/row
    unsigned* t1b     = (unsigned*)alloc((size_t)N * 32 * 4);  // bf16x2 x 32/row
    unsigned* g2b     = (unsigned*)alloc((size_t)N * 16 * 4);  // bf16x2 x 16/row

    k_hist<<<nPB, 256, 0, stream>>>(dst, E, mat, B, nPB);
    k_chunk_sums<<<nchunks, 256, 0, stream>>>(mat, M, sums);
    k_scan_sums<<<1, 1024, 0, stream>>>(sums, nchunks);
    k_scan_chunks<<<nchunks, 256, 0, stream>>>(mat, M, sums, mats);
    k_partition<<<nPB, 256, 0, stream>>>(src, dst, E, mats, packed, B, nPB);
    k_csrfill<<<B, 256, 0, stream>>>(packed, mats, colidx, rowptr2, dinv, N, E, B, nPB);

    k_gemm1<<<(N + 63) / 64, 256, 0, stream>>>(x, W1, dinv, g1b, N);
    k_agg1<<<(N + 3) / 4, 256, 0, stream>>>(g1b, rowptr2, colidx, dinv, b1, t1b, N);
    k_gemm2b<<<(N + 63) / 64, 256, 0, stream>>>(t1b, W2, dinv, g2b, N);
    k_agg2<<<(N + 3) / 4, 256, 0, stream>>>(g2b, rowptr2, colidx, dinv, b2, out, N);
}

// Round 10
// 287.504 us; speedup vs baseline: 1.1365x; 1.0175x over previous
//
#include <hip/hip_runtime.h>
#include <hip/hip_bf16.h>

// 2-layer GCN (PyG GCNConv) on MI355X.
// R10: k_gemm1 rebuild (R9 counters: 3.2M LDS bank conflicts from stride-128
// xs rows all starting at bank 0 -> 4-way conflict on every a-read; 64KB LDS
// -> 17% occupancy). Now: K tiled by 32, xs stride 36 (16B-aligned rows,
// start-bank 4r%32 -> only free 2-way aliasing), LDS 17.4KB -> ~8 blocks/CU.
// Everything else identical to R9 (de-fused pipeline).

#define IN_DIM 128
#define HID_DIM 64
#define OUT_DIM 32
#define BSHIFT 8
#define BSIZE 256
#define BMASK 255
#define PEB 8192   // edges per partition block

__device__ inline unsigned pack_bf16x2(float a, float b) {
    unsigned ua = __float_as_uint(a), ub = __float_as_uint(b);
    unsigned ra = (ua + 0x7fffu + ((ua >> 16) & 1u)) >> 16;        // RNE
    unsigned rb = (ub + 0x7fffu + ((ub >> 16) & 1u)) & 0xffff0000u;
    return (ra & 0xffffu) | rb;
}
#define BF_LO(w) __uint_as_float((w) << 16)
#define BF_HI(w) __uint_as_float((w) & 0xffff0000u)

#define ACC8(q)                                         \
    do {                                                \
        acc[0] += BF_LO((q).x); acc[1] += BF_HI((q).x); \
        acc[2] += BF_LO((q).y); acc[3] += BF_HI((q).y); \
        acc[4] += BF_LO((q).z); acc[5] += BF_HI((q).z); \
        acc[6] += BF_LO((q).w); acc[7] += BF_HI((q).w); \
    } while (0)

#define ACC4(q)                                         \
    do {                                                \
        acc[0] += BF_LO((q).x); acc[1] += BF_HI((q).x); \
        acc[2] += BF_LO((q).y); acc[3] += BF_HI((q).y); \
    } while (0)

// ---------------------------------------------------------------- pass 1: bucket histogram
__global__ __launch_bounds__(256) void k_hist(const int* __restrict__ dst, int E,
                                              int* __restrict__ mat, int B, int nPB) {
    __shared__ int cnt[512];
    int t = threadIdx.x;
    for (int b = t; b < B; b += 256) cnt[b] = 0;
    __syncthreads();
    int base = blockIdx.x * PEB;
#pragma unroll
    for (int i = 0; i < PEB / 256; ++i) {
        int e = base + i * 256 + t;
        if (e < E) atomicAdd(&cnt[dst[e] >> BSHIFT], 1);
    }
    __syncthreads();
    for (int b = t; b < B; b += 256) mat[b * nPB + blockIdx.x] = cnt[b];
}

// ---------------------------------------------------------------- scan (2-level)
__global__ void k_chunk_sums(const int* __restrict__ arr, int M, int* __restrict__ sums) {
    __shared__ int sdata[256];
    int t = threadIdx.x;
    int base = blockIdx.x * 1024 + t * 4;
    int s = 0;
#pragma unroll
    for (int i = 0; i < 4; ++i) {
        int idx = base + i;
        if (idx < M) s += arr[idx];
    }
    sdata[t] = s;
    __syncthreads();
    for (int off = 128; off > 0; off >>= 1) {
        if (t < off) sdata[t] += sdata[t + off];
        __syncthreads();
    }
    if (t == 0) sums[blockIdx.x] = sdata[0];
}

__global__ void k_scan_sums(int* __restrict__ sums, int nchunks) {
    __shared__ int buf[1024];
    int t = threadIdx.x;  // 1024 threads
    int v = (t < nchunks) ? sums[t] : 0;
    buf[t] = v;
    __syncthreads();
    for (int off = 1; off < 1024; off <<= 1) {
        int x = (t >= off) ? buf[t - off] : 0;
        __syncthreads();
        buf[t] += x;
        __syncthreads();
    }
    if (t < nchunks) sums[t] = buf[t] - v;  // exclusive
}

__global__ void k_scan_chunks(const int* __restrict__ arr, int M,
                              const int* __restrict__ sums, int* __restrict__ out) {
    __shared__ int tsum[256];
    int t = threadIdx.x;
    int idx0 = blockIdx.x * 1024 + t * 4;
    int v[4];
    int s = 0;
#pragma unroll
    for (int i = 0; i < 4; ++i) {
        int idx = idx0 + i;
        v[i] = (idx < M) ? arr[idx] : 0;
        s += v[i];
    }
    tsum[t] = s;
    __syncthreads();
    int mine = s;
    for (int off = 1; off < 256; off <<= 1) {
        int x = (t >= off) ? tsum[t - off] : 0;
        __syncthreads();
        tsum[t] += x;
        __syncthreads();
    }
    int run = tsum[t] - mine + sums[blockIdx.x];
#pragma unroll
    for (int i = 0; i < 4; ++i) {
        int idx = idx0 + i;
        if (idx < M) out[idx] = run;
        run += v[i];
    }
}

// ---------------------------------------------------------------- pass 2: partition
__global__ __launch_bounds__(256) void k_partition(const int* __restrict__ src,
                                                   const int* __restrict__ dst, int E,
                                                   const int* __restrict__ mats,
                                                   unsigned* __restrict__ packed,
                                                   int B, int nPB) {
    __shared__ int off[512];
    int t = threadIdx.x;
    for (int b = t; b < B; b += 256) off[b] = mats[b * nPB + blockIdx.x];
    __syncthreads();
    int base = blockIdx.x * PEB;
#pragma unroll
    for (int i = 0; i < PEB / 256; ++i) {
        int e = base + i * 256 + t;
        if (e < E) {
            int d = dst[e];
            int s = src[e];
            int slot = atomicAdd(&off[d >> BSHIFT], 1);
            packed[slot] = ((unsigned)s << BSHIFT) | (unsigned)(d & BMASK);
        }
    }
}

// ---------------------------------------------------------------- pass 3: per-bucket CSR build
__global__ __launch_bounds__(256) void k_csrfill(const unsigned* __restrict__ packed,
                                                 const int* __restrict__ mats,
                                                 int* __restrict__ colidx,
                                                 uint2* __restrict__ rowptr2,
                                                 float* __restrict__ dinv,
                                                 int N, int E, int B, int nPB) {
    __shared__ int ldeg[256];
    __shared__ int lscan[256];
    __shared__ int sexc[256];
    __shared__ int lfill[256];
    int t = threadIdx.x, bkt = blockIdx.x;
    int base = mats[bkt * nPB];
    int end  = (bkt + 1 < B) ? mats[(bkt + 1) * nPB] : E;
    ldeg[t] = 0;
    __syncthreads();
    for (int e = base + t; e < end; e += 256)
        atomicAdd(&ldeg[packed[e] & BMASK], 1);
    __syncthreads();
    int v = ldeg[t];
    lscan[t] = v;
    __syncthreads();
    for (int off = 1; off < 256; off <<= 1) {
        int x = (t >= off) ? lscan[t - off] : 0;
        __syncthreads();
        lscan[t] += x;
        __syncthreads();
    }
    int exc = lscan[t] - v;
    sexc[t] = exc;
    lfill[t] = 0;
    int node = (bkt << BSHIFT) + t;
    if (node < N) {
        rowptr2[node] = make_uint2((unsigned)(base + exc), (unsigned)(base + exc + v));
        dinv[node] = rsqrtf((float)v + 1.0f);
    }
    __syncthreads();
    for (int e = base + t; e < end; e += 256) {
        unsigned w = packed[e];
        int ld = w & BMASK;
        int pos = base + sexc[ld] + atomicAdd(&lfill[ld], 1);
        colidx[pos] = (int)(w >> BSHIFT);
    }
}

// ---------------------------------------------------------------- GEMM1: g1b = bf16((x @ W1) * dinv)
// K tiled by 32. LDS: xs 64x36 floats (9.2KB, stride 36 = 16B-aligned rows,
// row-start bank 4r%32) + ws 32x64 (8KB) = 17.4KB -> ~8 blocks/CU.
__global__ __launch_bounds__(256) void k_gemm1(const float* __restrict__ x,
                                               const float* __restrict__ W,
                                               const float* __restrict__ dinv,
                                               unsigned* __restrict__ g1b, int N) {
    __shared__ float xs[64 * 36];
    __shared__ float ws[32 * 64];
    int t = threadIdx.x;
    int row0 = blockIdx.x * 64;
    int tx = t & 15;   // 16 col groups x 4 cols
    int ty = t >> 4;   // 16 row groups x 4 rows
    int sr = t >> 3, sc = t & 7;  // staging: 32 rows x 8 float4

    float acc[4][4] = {};
    for (int kt = 0; kt < 4; ++kt) {
        // stage W tile (32 x 64 = 512 float4)
        const float4* W4 = (const float4*)(W + kt * 32 * HID_DIM);
        float4* ws4 = (float4*)ws;
        ws4[t] = W4[t];
        ws4[t + 256] = W4[t + 256];
        // stage x tile (64 rows x 32 cols), two halves of 32 rows
#pragma unroll
        for (int half = 0; half < 2; ++half) {
            int r = sr + half * 32;
            int row = row0 + r;
            float4 val = make_float4(0.f, 0.f, 0.f, 0.f);
            if (row < N)
                val = *(const float4*)&x[(size_t)row * IN_DIM + kt * 32 + sc * 4];
            *(float4*)&xs[r * 36 + sc * 4] = val;
        }
        __syncthreads();
#pragma unroll
        for (int k = 0; k < 32; k += 4) {
            float a[4][4], b[4][4];
#pragma unroll
            for (int i = 0; i < 4; ++i)
                *(float4*)a[i] = *(const float4*)&xs[(ty * 4 + i) * 36 + k];
#pragma unroll
            for (int kk = 0; kk < 4; ++kk)
                *(float4*)b[kk] = *(const float4*)&ws[(k + kk) * HID_DIM + tx * 4];
#pragma unroll
            for (int i = 0; i < 4; ++i)
#pragma unroll
                for (int kk = 0; kk < 4; ++kk)
#pragma unroll
                    for (int j = 0; j < 4; ++j)
                        acc[i][j] += a[i][kk] * b[kk][j];
        }
        __syncthreads();
    }
#pragma unroll
    for (int i = 0; i < 4; ++i) {
        int row = row0 + ty * 4 + i;
        if (row < N) {
            float dv = dinv[row];
            uint2 u;
            u.x = pack_bf16x2(acc[i][0] * dv, acc[i][1] * dv);
            u.y = pack_bf16x2(acc[i][2] * dv, acc[i][3] * dv);
            *(uint2*)&g1b[(size_t)row * 32 + tx * 2] = u;
        }
    }
}

// ---------------------------------------------------------------- agg layer 1 (unfused)
// One wave per node. Gather: lane = (grp 0..7, fp 0..7); lane loads uint4 =
// 16B, 8 lanes/row -> 8 edges per load inst, 16 edges in flight.
__global__ __launch_bounds__(256) void k_agg1(const unsigned* __restrict__ g1,
                                              const uint2* __restrict__ rowptr2,
                                              const int* __restrict__ colidx,
                                              const float* __restrict__ dinv,
                                              const float* __restrict__ b1,
                                              unsigned* __restrict__ t1b, int N) {
    int t = threadIdx.x;
    int dd = (blockIdx.x * 256 + t) >> 6;
    bool live = dd < N;
    int d = live ? dd : N - 1;
    int lane = t & 63, grp = lane >> 3, fp = lane & 7;

    uint2 be = rowptr2[d];
    float acc[8] = {};
    int e = (int)be.x, end = (int)be.y;
    for (; e + 16 <= end; e += 16) {
        int s0 = colidx[e + grp];
        int s1 = colidx[e + 8 + grp];
        uint4 q0 = *(const uint4*)&g1[(size_t)s0 * 32 + fp * 4];
        uint4 q1 = *(const uint4*)&g1[(size_t)s1 * 32 + fp * 4];
        ACC8(q0);
        ACC8(q1);
    }
    for (; e + 8 <= end; e += 8) {
        int s = colidx[e + grp];
        uint4 q = *(const uint4*)&g1[(size_t)s * 32 + fp * 4];
        ACC8(q);
    }
    if (e < end) {  // 1..7 edges left
        int cnt = end - e;
        int s = colidx[(grp < cnt) ? e + grp : e];
        uint4 q = *(const uint4*)&g1[(size_t)s * 32 + fp * 4];
        if (grp < cnt) ACC8(q);
    }
#pragma unroll
    for (int i = 0; i < 8; ++i) {
        acc[i] += __shfl_xor(acc[i], 8);
        acc[i] += __shfl_xor(acc[i], 16);
        acc[i] += __shfl_xor(acc[i], 32);
    }

    // self-loop + scale + bias + relu
    uint4 sq = *(const uint4*)&g1[(size_t)d * 32 + fp * 4];
    ACC8(sq);
    float dv = dinv[d];
    float4 bb0 = ((const float4*)b1)[fp * 2];
    float4 bb1 = ((const float4*)b1)[fp * 2 + 1];
    float v0 = fmaxf(dv * acc[0] + bb0.x, 0.f);
    float v1 = fmaxf(dv * acc[1] + bb0.y, 0.f);
    float v2 = fmaxf(dv * acc[2] + bb0.z, 0.f);
    float v3 = fmaxf(dv * acc[3] + bb0.w, 0.f);
    float v4 = fmaxf(dv * acc[4] + bb1.x, 0.f);
    float v5 = fmaxf(dv * acc[5] + bb1.y, 0.f);
    float v6 = fmaxf(dv * acc[6] + bb1.z, 0.f);
    float v7 = fmaxf(dv * acc[7] + bb1.w, 0.f);
    if (live && grp == 0) {
        uint4 u;
        u.x = pack_bf16x2(v0, v1);
        u.y = pack_bf16x2(v2, v3);
        u.z = pack_bf16x2(v4, v5);
        u.w = pack_bf16x2(v6, v7);
        *(uint4*)&t1b[(size_t)dd * 32 + fp * 4] = u;
    }
}

// ---------------------------------------------------------------- GEMM2: g2b = bf16((t1b @ W2) * dinv)
__global__ __launch_bounds__(256) void k_gemm2b(const unsigned* __restrict__ t1b,
                                                const float* __restrict__ W2,
                                                const float* __restrict__ dinv,
                                                unsigned* __restrict__ g2b, int N) {
    __shared__ unsigned t1s[64 * 33];       // bf16x2, row stride 33 (+1 pad)
    __shared__ float W2s[HID_DIM * OUT_DIM];
    int t = threadIdx.x;
    int row0 = blockIdx.x * 64;

    const float4* W24 = (const float4*)W2;  // 512 float4
    float4* W2s4 = (float4*)W2s;
#pragma unroll
    for (int i = 0; i < 2; ++i) W2s4[t + 256 * i] = W24[t + 256 * i];
#pragma unroll
    for (int i = 0; i < 8; ++i) {           // 2048 uints
        int l = t + 256 * i;
        int r = l >> 5, c = l & 31;
        int row = row0 + r;
        unsigned val = 0;
        if (row < N) val = t1b[(size_t)row * 32 + c];
        t1s[r * 33 + c] = val;
    }
    __syncthreads();

    int r = t >> 2, q = t & 3;
    float acc[8] = {};
    const unsigned* trow = &t1s[r * 33];
    const float* wbase = &W2s[q * 8];
#pragma unroll
    for (int kp = 0; kp < 32; ++kp) {
        unsigned u = trow[kp];
        float a0 = BF_LO(u), a1 = BF_HI(u);
        float4 w00 = *(const float4*)&wbase[(2 * kp) * OUT_DIM];
        float4 w01 = *(const float4*)&wbase[(2 * kp) * OUT_DIM + 4];
        float4 w10 = *(const float4*)&wbase[(2 * kp + 1) * OUT_DIM];
        float4 w11 = *(const float4*)&wbase[(2 * kp + 1) * OUT_DIM + 4];
        acc[0] += a0 * w00.x + a1 * w10.x;
        acc[1] += a0 * w00.y + a1 * w10.y;
        acc[2] += a0 * w00.z + a1 * w10.z;
        acc[3] += a0 * w00.w + a1 * w10.w;
        acc[4] += a0 * w01.x + a1 * w11.x;
        acc[5] += a0 * w01.y + a1 * w11.y;
        acc[6] += a0 * w01.z + a1 * w11.z;
        acc[7] += a0 * w01.w + a1 * w11.w;
    }
    int row = row0 + r;
    if (row < N) {
        float dv = dinv[row];
        uint4 u;
        u.x = pack_bf16x2(acc[0] * dv, acc[1] * dv);
        u.y = pack_bf16x2(acc[2] * dv, acc[3] * dv);
        u.z = pack_bf16x2(acc[4] * dv, acc[5] * dv);
        u.w = pack_bf16x2(acc[6] * dv, acc[7] * dv);
        *(uint4*)&g2b[(size_t)row * 16 + q * 4] = u;
    }
}

// ---------------------------------------------------------------- agg layer 2
__global__ __launch_bounds__(256) void k_agg2(const unsigned* __restrict__ g2,
                                              const uint2* __restrict__ rowptr2,
                                              const int* __restrict__ colidx,
                                              const float* __restrict__ dinv,
                                              const float* __restrict__ b2,
                                              float* __restrict__ out, int N) {
    int t = threadIdx.x;
    int dd = (blockIdx.x * 256 + t) >> 6;
    bool live = dd < N;
    int d = live ? dd : N - 1;
    int lane = t & 63, grp = lane >> 3, fp = lane & 7;

    uint2 be = rowptr2[d];
    float acc[4] = {};
    int e = (int)be.x, end = (int)be.y;
    for (; e + 16 <= end; e += 16) {
        int s0 = colidx[e + grp];
        int s1 = colidx[e + 8 + grp];
        uint2 q0 = *(const uint2*)&g2[(size_t)s0 * 16 + fp * 2];
        uint2 q1 = *(const uint2*)&g2[(size_t)s1 * 16 + fp * 2];
        ACC4(q0);
        ACC4(q1);
    }
    for (; e + 8 <= end; e += 8) {
        int s = colidx[e + grp];
        uint2 q = *(const uint2*)&g2[(size_t)s * 16 + fp * 2];
        ACC4(q);
    }
    if (e < end) {  // 1..7 edges left
        int cnt = end - e;
        int s = colidx[(grp < cnt) ? e + grp : e];
        uint2 q = *(const uint2*)&g2[(size_t)s * 16 + fp * 2];
        if (grp < cnt) ACC4(q);
    }
#pragma unroll
    for (int i = 0; i < 4; ++i) {
        acc[i] += __shfl_xor(acc[i], 8);
        acc[i] += __shfl_xor(acc[i], 16);
        acc[i] += __shfl_xor(acc[i], 32);
    }
    // self-loop + epilogue
    uint2 sq = *(const uint2*)&g2[(size_t)d * 16 + fp * 2];
    ACC4(sq);
    float dv = dinv[d];
    float4 bb = ((const float4*)b2)[fp];
    if (live && grp == 0) {
        float4 r;
        r.x = dv * acc[0] + bb.x;
        r.y = dv * acc[1] + bb.y;
        r.z = dv * acc[2] + bb.z;
        r.w = dv * acc[3] + bb.w;
        *(float4*)&out[(size_t)dd * OUT_DIM + fp * 4] = r;
    }
}

// ---------------------------------------------------------------- launch
extern "C" void kernel_launch(void* const* d_in, const int* in_sizes, int n_in,
                              void* d_out, int out_size, void* d_ws, size_t ws_size,
                              hipStream_t stream) {
    const float* x  = (const float*)d_in[0];
    const int*   ei = (const int*)d_in[1];
    const float* W1 = (const float*)d_in[2];
    const float* b1 = (const float*)d_in[3];
    const float* W2 = (const float*)d_in[4];
    const float* b2 = (const float*)d_in[5];
    float* out = (float*)d_out;

    const int N = in_sizes[0] / IN_DIM;
    const int E = in_sizes[1] / 2;
    const int* src = ei;
    const int* dst = ei + E;

    const int B   = (N + BSIZE - 1) / BSIZE;
    const int nPB = (E + PEB - 1) / PEB;
    const int M   = B * nPB;
    const int nchunks = (M + 1023) / 1024;

    char* p = (char*)d_ws;
    auto alloc = [&](size_t bytes) -> void* {
        void* r = (void*)p;
        p += (bytes + 255) & ~(size_t)255;
        return r;
    };
    int*      mat     = (int*)alloc((size_t)M * 4);
    int*      mats    = (int*)alloc((size_t)M * 4);
    int*      sums    = (int*)alloc((size_t)nchunks * 4);
    unsigned* packed  = (unsigned*)alloc((size_t)E * 4);
    int*      colidx  = (int*)alloc((size_t)E * 4);
    uint2*    rowptr2 = (uint2*)alloc((size_t)N * 8);
    float*    dinv    = (float*)alloc((size_t)N * 4);
    unsigned* g1b     = (unsigned*)alloc((size_t)N * 32 * 4);  // bf16x2 x 32/row
    unsigned* t1b     = (unsigned*)alloc((size_t)N * 32 * 4);  // bf16x2 x 32/row
    unsigned* g2b     = (unsigned*)alloc((size_t)N * 16 * 4);  // bf16x2 x 16/row

    k_hist<<<nPB, 256, 0, stream>>>(dst, E, mat, B, nPB);
    k_chunk_sums<<<nchunks, 256, 0, stream>>>(mat, M, sums);
    k_scan_sums<<<1, 1024, 0, stream>>>(sums, nchunks);
    k_scan_chunks<<<nchunks, 256, 0, stream>>>(mat, M, sums, mats);
    k_partition<<<nPB, 256, 0, stream>>>(src, dst, E, mats, packed, B, nPB);
    k_csrfill<<<B, 256, 0, stream>>>(packed, mats, colidx, rowptr2, dinv, N, E, B, nPB);

    k_gemm1<<<(N + 63) / 64, 256, 0, stream>>>(x, W1, dinv, g1b, N);
    k_agg1<<<(N + 3) / 4, 256, 0, stream>>>(g1b, rowptr2, colidx, dinv, b1, t1b, N);
    k_gemm2b<<<(N + 63) / 64, 256, 0, stream>>>(t1b, W2, dinv, g2b, N);
    k_agg2<<<(N + 3) / 4, 256, 0, stream>>>(g2b, rowptr2, colidx, dinv, b2, out, N);
}

// Round 11
// 283.357 us; speedup vs baseline: 1.1532x; 1.0146x over previous
//
#include <hip/hip_runtime.h>
#include <hip/hip_bf16.h>

// 2-layer GCN (PyG GCNConv) on MI355X.
// R11: (1) CSR front-end collapsed 5 dispatches -> 1: buckets get fixed
// 8192-slot segments; k_partition counts in LDS then reserves via one global
// atomicAdd(bfill[b]) per block-bucket -> kills k_hist + 3 scan kernels.
// (2) agg kernels accumulate into float2 ext-vectors (v_pk_add_f32): ACC8
// 16 -> ~12 VALU (R10: agg1 VALUBusy 60% = issue-bound unpack+add chain).
// Gather loop structure otherwise untouched (R8 lesson: it's fragile).

#define IN_DIM 128
#define HID_DIM 64
#define OUT_DIM 32
#define BSHIFT 8
#define BSIZE 256
#define BMASK 255
#define PEB 4096      // edges per partition block
#define CAPSHIFT 13   // 8192 slots per bucket segment (expected max ~4500)

typedef __attribute__((ext_vector_type(2))) float v2f;

__device__ inline unsigned pack_bf16x2(float a, float b) {
    unsigned ua = __float_as_uint(a), ub = __float_as_uint(b);
    unsigned ra = (ua + 0x7fffu + ((ua >> 16) & 1u)) >> 16;        // RNE
    unsigned rb = (ub + 0x7fffu + ((ub >> 16) & 1u)) & 0xffff0000u;
    return (ra & 0xffffu) | rb;
}
#define BF_LO(w) __uint_as_float((w) << 16)
#define BF_HI(w) __uint_as_float((w) & 0xffff0000u)

__device__ inline v2f bfpair(unsigned u) {
    v2f r;
    r.x = __uint_as_float(u << 16);
    r.y = __uint_as_float(u & 0xffff0000u);
    return r;
}

#define ACC8(q)                                         \
    do {                                                \
        acc[0] += BF_LO((q).x); acc[1] += BF_HI((q).x); \
        acc[2] += BF_LO((q).y); acc[3] += BF_HI((q).y); \
        acc[4] += BF_LO((q).z); acc[5] += BF_HI((q).z); \
        acc[6] += BF_LO((q).w); acc[7] += BF_HI((q).w); \
    } while (0)

#define ACC4(q)                                         \
    do {                                                \
        acc[0] += BF_LO((q).x); acc[1] += BF_HI((q).x); \
        acc[2] += BF_LO((q).y); acc[3] += BF_HI((q).y); \
    } while (0)

// ---------------------------------------------------------------- partition (single pass kernel)
// Pass 1: LDS bucket histogram of this block's PEB edges.
// Reserve: one global atomicAdd per (block,bucket) -> contiguous per-bucket
// segments at [b<<CAPSHIFT, ...). Pass 2: write packed words (dst re-read L2-hot).
__global__ __launch_bounds__(256) void k_partition(const int* __restrict__ src,
                                                   const int* __restrict__ dst, int E,
                                                   int* __restrict__ bfill,
                                                   unsigned* __restrict__ packed, int B) {
    __shared__ int cnt[512];
    __shared__ int off[512];
    int t = threadIdx.x;
    for (int b = t; b < 512; b += 256) cnt[b] = 0;
    __syncthreads();
    int base = blockIdx.x * PEB;
#pragma unroll
    for (int i = 0; i < PEB / 256; ++i) {
        int e = base + i * 256 + t;
        if (e < E) atomicAdd(&cnt[dst[e] >> BSHIFT], 1);
    }
    __syncthreads();
    for (int b = t; b < B; b += 256) {
        int c = cnt[b];
        int o = c ? atomicAdd(&bfill[b], c) : 0;
        off[b] = (b << CAPSHIFT) + o;
    }
    __syncthreads();
#pragma unroll
    for (int i = 0; i < PEB / 256; ++i) {
        int e = base + i * 256 + t;
        if (e < E) {
            int d = dst[e];
            int s = src[e];
            int slot = atomicAdd(&off[d >> BSHIFT], 1);
            packed[slot] = ((unsigned)s << BSHIFT) | (unsigned)(d & BMASK);
        }
    }
}

// ---------------------------------------------------------------- per-bucket CSR build
__global__ __launch_bounds__(256) void k_csrfill(const unsigned* __restrict__ packed,
                                                 const int* __restrict__ bfill,
                                                 int* __restrict__ colidx,
                                                 uint2* __restrict__ rowptr2,
                                                 float* __restrict__ dinv,
                                                 int N, int B) {
    __shared__ int ldeg[256];
    __shared__ int lscan[256];
    __shared__ int sexc[256];
    __shared__ int lfill[256];
    int t = threadIdx.x, bkt = blockIdx.x;
    int base = bkt << CAPSHIFT;
    int end  = base + bfill[bkt];
    ldeg[t] = 0;
    __syncthreads();
    for (int e = base + t; e < end; e += 256)
        atomicAdd(&ldeg[packed[e] & BMASK], 1);
    __syncthreads();
    int v = ldeg[t];
    lscan[t] = v;
    __syncthreads();
    for (int off = 1; off < 256; off <<= 1) {
        int x = (t >= off) ? lscan[t - off] : 0;
        __syncthreads();
        lscan[t] += x;
        __syncthreads();
    }
    int exc = lscan[t] - v;
    sexc[t] = exc;
    lfill[t] = 0;
    int node = (bkt << BSHIFT) + t;
    if (node < N) {
        rowptr2[node] = make_uint2((unsigned)(base + exc), (unsigned)(base + exc + v));
        dinv[node] = rsqrtf((float)v + 1.0f);
    }
    __syncthreads();
    for (int e = base + t; e < end; e += 256) {
        unsigned w = packed[e];
        int ld = w & BMASK;
        int pos = base + sexc[ld] + atomicAdd(&lfill[ld], 1);
        colidx[pos] = (int)(w >> BSHIFT);
    }
}

// ---------------------------------------------------------------- GEMM1: g1b = bf16((x @ W1) * dinv)
// K tiled by 32. LDS: xs 64x36 (stride 36 -> start-bank 4r%32) + ws 32x64 = 17.4KB.
__global__ __launch_bounds__(256) void k_gemm1(const float* __restrict__ x,
                                               const float* __restrict__ W,
                                               const float* __restrict__ dinv,
                                               unsigned* __restrict__ g1b, int N) {
    __shared__ float xs[64 * 36];
    __shared__ float ws[32 * 64];
    int t = threadIdx.x;
    int row0 = blockIdx.x * 64;
    int tx = t & 15;
    int ty = t >> 4;
    int sr = t >> 3, sc = t & 7;

    float acc[4][4] = {};
    for (int kt = 0; kt < 4; ++kt) {
        const float4* W4 = (const float4*)(W + kt * 32 * HID_DIM);
        float4* ws4 = (float4*)ws;
        ws4[t] = W4[t];
        ws4[t + 256] = W4[t + 256];
#pragma unroll
        for (int half = 0; half < 2; ++half) {
            int r = sr + half * 32;
            int row = row0 + r;
            float4 val = make_float4(0.f, 0.f, 0.f, 0.f);
            if (row < N)
                val = *(const float4*)&x[(size_t)row * IN_DIM + kt * 32 + sc * 4];
            *(float4*)&xs[r * 36 + sc * 4] = val;
        }
        __syncthreads();
#pragma unroll
        for (int k = 0; k < 32; k += 4) {
            float a[4][4], b[4][4];
#pragma unroll
            for (int i = 0; i < 4; ++i)
                *(float4*)a[i] = *(const float4*)&xs[(ty * 4 + i) * 36 + k];
#pragma unroll
            for (int kk = 0; kk < 4; ++kk)
                *(float4*)b[kk] = *(const float4*)&ws[(k + kk) * HID_DIM + tx * 4];
#pragma unroll
            for (int i = 0; i < 4; ++i)
#pragma unroll
                for (int kk = 0; kk < 4; ++kk)
#pragma unroll
                    for (int j = 0; j < 4; ++j)
                        acc[i][j] += a[i][kk] * b[kk][j];
        }
        __syncthreads();
    }
#pragma unroll
    for (int i = 0; i < 4; ++i) {
        int row = row0 + ty * 4 + i;
        if (row < N) {
            float dv = dinv[row];
            uint2 u;
            u.x = pack_bf16x2(acc[i][0] * dv, acc[i][1] * dv);
            u.y = pack_bf16x2(acc[i][2] * dv, acc[i][3] * dv);
            *(uint2*)&g1b[(size_t)row * 32 + tx * 2] = u;
        }
    }
}

// ---------------------------------------------------------------- agg layer 1 (unfused)
// One wave per node. lane = (grp 0..7, fp 0..7); lane loads uint4 = 16B,
// 8 lanes/row -> 8 edges per load inst, 16 edges in flight.
// Accumulate into float2 vectors -> v_pk_add_f32 (ACC8: 16 -> 12 VALU).
__global__ __launch_bounds__(256) void k_agg1(const unsigned* __restrict__ g1,
                                              const uint2* __restrict__ rowptr2,
                                              const int* __restrict__ colidx,
                                              const float* __restrict__ dinv,
                                              const float* __restrict__ b1,
                                              unsigned* __restrict__ t1b, int N) {
    int t = threadIdx.x;
    int dd = (blockIdx.x * 256 + t) >> 6;
    bool live = dd < N;
    int d = live ? dd : N - 1;
    int lane = t & 63, grp = lane >> 3, fp = lane & 7;

    uint2 be = rowptr2[d];
    v2f a01 = {0.f, 0.f}, a23 = {0.f, 0.f}, a45 = {0.f, 0.f}, a67 = {0.f, 0.f};
#define ACC8V(q)                                   \
    do {                                           \
        a01 += bfpair((q).x); a23 += bfpair((q).y);\
        a45 += bfpair((q).z); a67 += bfpair((q).w);\
    } while (0)
    int e = (int)be.x, end = (int)be.y;
    for (; e + 16 <= end; e += 16) {
        int s0 = colidx[e + grp];
        int s1 = colidx[e + 8 + grp];
        uint4 q0 = *(const uint4*)&g1[(size_t)s0 * 32 + fp * 4];
        uint4 q1 = *(const uint4*)&g1[(size_t)s1 * 32 + fp * 4];
        ACC8V(q0);
        ACC8V(q1);
    }
    for (; e + 8 <= end; e += 8) {
        int s = colidx[e + grp];
        uint4 q = *(const uint4*)&g1[(size_t)s * 32 + fp * 4];
        ACC8V(q);
    }
    if (e < end) {  // 1..7 edges left
        int cnt = end - e;
        int s = colidx[(grp < cnt) ? e + grp : e];
        uint4 q = *(const uint4*)&g1[(size_t)s * 32 + fp * 4];
        if (grp < cnt) ACC8V(q);
    }
#undef ACC8V
    float acc[8] = {a01.x, a01.y, a23.x, a23.y, a45.x, a45.y, a67.x, a67.y};
#pragma unroll
    for (int i = 0; i < 8; ++i) {
        acc[i] += __shfl_xor(acc[i], 8);
        acc[i] += __shfl_xor(acc[i], 16);
        acc[i] += __shfl_xor(acc[i], 32);
    }

    // self-loop + scale + bias + relu
    uint4 sq = *(const uint4*)&g1[(size_t)d * 32 + fp * 4];
    ACC8(sq);
    float dv = dinv[d];
    float4 bb0 = ((const float4*)b1)[fp * 2];
    float4 bb1 = ((const float4*)b1)[fp * 2 + 1];
    float v0 = fmaxf(dv * acc[0] + bb0.x, 0.f);
    float v1 = fmaxf(dv * acc[1] + bb0.y, 0.f);
    float v2 = fmaxf(dv * acc[2] + bb0.z, 0.f);
    float v3 = fmaxf(dv * acc[3] + bb0.w, 0.f);
    float v4 = fmaxf(dv * acc[4] + bb1.x, 0.f);
    float v5 = fmaxf(dv * acc[5] + bb1.y, 0.f);
    float v6 = fmaxf(dv * acc[6] + bb1.z, 0.f);
    float v7 = fmaxf(dv * acc[7] + bb1.w, 0.f);
    if (live && grp == 0) {
        uint4 u;
        u.x = pack_bf16x2(v0, v1);
        u.y = pack_bf16x2(v2, v3);
        u.z = pack_bf16x2(v4, v5);
        u.w = pack_bf16x2(v6, v7);
        *(uint4*)&t1b[(size_t)dd * 32 + fp * 4] = u;
    }
}

// ---------------------------------------------------------------- GEMM2: g2b = bf16((t1b @ W2) * dinv)
__global__ __launch_bounds__(256) void k_gemm2b(const unsigned* __restrict__ t1b,
                                                const float* __restrict__ W2,
                                                const float* __restrict__ dinv,
                                                unsigned* __restrict__ g2b, int N) {
    __shared__ unsigned t1s[64 * 33];       // bf16x2, row stride 33 (+1 pad)
    __shared__ float W2s[HID_DIM * OUT_DIM];
    int t = threadIdx.x;
    int row0 = blockIdx.x * 64;

    const float4* W24 = (const float4*)W2;  // 512 float4
    float4* W2s4 = (float4*)W2s;
#pragma unroll
    for (int i = 0; i < 2; ++i) W2s4[t + 256 * i] = W24[t + 256 * i];
#pragma unroll
    for (int i = 0; i < 8; ++i) {           // 2048 uints
        int l = t + 256 * i;
        int r = l >> 5, c = l & 31;
        int row = row0 + r;
        unsigned val = 0;
        if (row < N) val = t1b[(size_t)row * 32 + c];
        t1s[r * 33 + c] = val;
    }
    __syncthreads();

    int r = t >> 2, q = t & 3;
    float acc[8] = {};
    const unsigned* trow = &t1s[r * 33];
    const float* wbase = &W2s[q * 8];
#pragma unroll
    for (int kp = 0; kp < 32; ++kp) {
        unsigned u = trow[kp];
        float a0 = BF_LO(u), a1 = BF_HI(u);
        float4 w00 = *(const float4*)&wbase[(2 * kp) * OUT_DIM];
        float4 w01 = *(const float4*)&wbase[(2 * kp) * OUT_DIM + 4];
        float4 w10 = *(const float4*)&wbase[(2 * kp + 1) * OUT_DIM];
        float4 w11 = *(const float4*)&wbase[(2 * kp + 1) * OUT_DIM + 4];
        acc[0] += a0 * w00.x + a1 * w10.x;
        acc[1] += a0 * w00.y + a1 * w10.y;
        acc[2] += a0 * w00.z + a1 * w10.z;
        acc[3] += a0 * w00.w + a1 * w10.w;
        acc[4] += a0 * w01.x + a1 * w11.x;
        acc[5] += a0 * w01.y + a1 * w11.y;
        acc[6] += a0 * w01.z + a1 * w11.z;
        acc[7] += a0 * w01.w + a1 * w11.w;
    }
    int row = row0 + r;
    if (row < N) {
        float dv = dinv[row];
        uint4 u;
        u.x = pack_bf16x2(acc[0] * dv, acc[1] * dv);
        u.y = pack_bf16x2(acc[2] * dv, acc[3] * dv);
        u.z = pack_bf16x2(acc[4] * dv, acc[5] * dv);
        u.w = pack_bf16x2(acc[6] * dv, acc[7] * dv);
        *(uint4*)&g2b[(size_t)row * 16 + q * 4] = u;
    }
}

// ---------------------------------------------------------------- agg layer 2
// One wave per node. lane = (grp 0..7, fp 0..7); lane loads uint2 = 8B,
// 8 lanes cover one 64B row. float2 packed accumulate.
__global__ __launch_bounds__(256) void k_agg2(const unsigned* __restrict__ g2,
                                              const uint2* __restrict__ rowptr2,
                                              const int* __restrict__ colidx,
                                              const float* __restrict__ dinv,
                                              const float* __restrict__ b2,
                                              float* __restrict__ out, int N) {
    int t = threadIdx.x;
    int dd = (blockIdx.x * 256 + t) >> 6;
    bool live = dd < N;
    int d = live ? dd : N - 1;
    int lane = t & 63, grp = lane >> 3, fp = lane & 7;

    uint2 be = rowptr2[d];
    v2f a01 = {0.f, 0.f}, a23 = {0.f, 0.f};
#define ACC4V(q)                                   \
    do {                                           \
        a01 += bfpair((q).x); a23 += bfpair((q).y);\
    } while (0)
    int e = (int)be.x, end = (int)be.y;
    for (; e + 16 <= end; e += 16) {
        int s0 = colidx[e + grp];
        int s1 = colidx[e + 8 + grp];
        uint2 q0 = *(const uint2*)&g2[(size_t)s0 * 16 + fp * 2];
        uint2 q1 = *(const uint2*)&g2[(size_t)s1 * 16 + fp * 2];
        ACC4V(q0);
        ACC4V(q1);
    }
    for (; e + 8 <= end; e += 8) {
        int s = colidx[e + grp];
        uint2 q = *(const uint2*)&g2[(size_t)s * 16 + fp * 2];
        ACC4V(q);
    }
    if (e < end) {  // 1..7 edges left
        int cnt = end - e;
        int s = colidx[(grp < cnt) ? e + grp : e];
        uint2 q = *(const uint2*)&g2[(size_t)s * 16 + fp * 2];
        if (grp < cnt) ACC4V(q);
    }
#undef ACC4V
    float acc[4] = {a01.x, a01.y, a23.x, a23.y};
#pragma unroll
    for (int i = 0; i < 4; ++i) {
        acc[i] += __shfl_xor(acc[i], 8);
        acc[i] += __shfl_xor(acc[i], 16);
        acc[i] += __shfl_xor(acc[i], 32);
    }
    // self-loop + epilogue
    uint2 sq = *(const uint2*)&g2[(size_t)d * 16 + fp * 2];
    ACC4(sq);
    float dv = dinv[d];
    float4 bb = ((const float4*)b2)[fp];
    if (live && grp == 0) {
        float4 r;
        r.x = dv * acc[0] + bb.x;
        r.y = dv * acc[1] + bb.y;
        r.z = dv * acc[2] + bb.z;
        r.w = dv * acc[3] + bb.w;
        *(float4*)&out[(size_t)dd * OUT_DIM + fp * 4] = r;
    }
}

// ---------------------------------------------------------------- launch
extern "C" void kernel_launch(void* const* d_in, const int* in_sizes, int n_in,
                              void* d_out, int out_size, void* d_ws, size_t ws_size,
                              hipStream_t stream) {
    const float* x  = (const float*)d_in[0];
    const int*   ei = (const int*)d_in[1];
    const float* W1 = (const float*)d_in[2];
    const float* b1 = (const float*)d_in[3];
    const float* W2 = (const float*)d_in[4];
    const float* b2 = (const float*)d_in[5];
    float* out = (float*)d_out;

    const int N = in_sizes[0] / IN_DIM;
    const int E = in_sizes[1] / 2;
    const int* src = ei;
    const int* dst = ei + E;

    const int B   = (N + BSIZE - 1) / BSIZE;          // buckets
    const int nPB = (E + PEB - 1) / PEB;              // partition blocks
    const size_t SLOTS = (size_t)B << CAPSHIFT;       // segmented edge slots

    char* p = (char*)d_ws;
    auto alloc = [&](size_t bytes) -> void* {
        void* r = (void*)p;
        p += (bytes + 255) & ~(size_t)255;
        return r;
    };
    int*      bfill   = (int*)alloc((size_t)B * 4);
    unsigned* packed  = (unsigned*)alloc(SLOTS * 4);
    int*      colidx  = (int*)alloc(SLOTS * 4);
    uint2*    rowptr2 = (uint2*)alloc((size_t)N * 8);
    float*    dinv    = (float*)alloc((size_t)N * 4);
    unsigned* g1b     = (unsigned*)alloc((size_t)N * 32 * 4);  // bf16x2 x 32/row
    unsigned* t1b     = (unsigned*)alloc((size_t)N * 32 * 4);  // bf16x2 x 32/row
    unsigned* g2b     = (unsigned*)alloc((size_t)N * 16 * 4);  // bf16x2 x 16/row

    hipMemsetAsync(bfill, 0, (size_t)B * 4, stream);
    k_partition<<<nPB, 256, 0, stream>>>(src, dst, E, bfill, packed, B);
    k_csrfill<<<B, 256, 0, stream>>>(packed, bfill, colidx, rowptr2, dinv, N, B);

    k_gemm1<<<(N + 63) / 64, 256, 0, stream>>>(x, W1, dinv, g1b, N);
    k_agg1<<<(N + 3) / 4, 256, 0, stream>>>(g1b, rowptr2, colidx, dinv, b1, t1b, N);
    k_gemm2b<<<(N + 63) / 64, 256, 0, stream>>>(t1b, W2, dinv, g2b, N);
    k_agg2<<<(N + 3) / 4, 256, 0, stream>>>(g2b, rowptr2, colidx, dinv, b2, out, N);
}

// Round 12
// 259.276 us; speedup vs baseline: 1.2603x; 1.0929x over previous
//
#include <hip/hip_runtime.h>
#include <hip/hip_bf16.h>

// 2-layer GCN (PyG GCNConv) on MI355X.
// R12: multi-node-per-wave aggregation. With avg degree 16, per-node fixed
// cost (prologue + 24-shfl reduce + epilogue ~60 inst) dominated the ~35
// gather insts. Now:
//   k_agg1: node per 32-lane half (2 nodes/wave): reduce 24->8 shfl/node,
//           same uint4 gather (8 edges in flight per node).
//   k_agg2: node per 16-lane quarter (4 nodes/wave), uint4 rows (4 lanes/row):
//           reduce 12->4 shfl/node, 32 edges in flight per wave.
// 128-thread blocks (2 waves) keep full waves/CU under the workgroup cap.
// Front-end (R11 single-dispatch partition + csrfill), gemm1, gemm2b unchanged.

#define IN_DIM 128
#define HID_DIM 64
#define OUT_DIM 32
#define BSHIFT 8
#define BSIZE 256
#define BMASK 255
#define PEB 4096      // edges per partition block
#define CAPSHIFT 13   // 8192 slots per bucket segment (expected max ~4500)

typedef __attribute__((ext_vector_type(2))) float v2f;

__device__ inline unsigned pack_bf16x2(float a, float b) {
    unsigned ua = __float_as_uint(a), ub = __float_as_uint(b);
    unsigned ra = (ua + 0x7fffu + ((ua >> 16) & 1u)) >> 16;        // RNE
    unsigned rb = (ub + 0x7fffu + ((ub >> 16) & 1u)) & 0xffff0000u;
    return (ra & 0xffffu) | rb;
}
#define BF_LO(w) __uint_as_float((w) << 16)
#define BF_HI(w) __uint_as_float((w) & 0xffff0000u)

__device__ inline v2f bfpair(unsigned u) {
    v2f r;
    r.x = __uint_as_float(u << 16);
    r.y = __uint_as_float(u & 0xffff0000u);
    return r;
}

#define ACC8(q)                                         \
    do {                                                \
        acc[0] += BF_LO((q).x); acc[1] += BF_HI((q).x); \
        acc[2] += BF_LO((q).y); acc[3] += BF_HI((q).y); \
        acc[4] += BF_LO((q).z); acc[5] += BF_HI((q).z); \
        acc[6] += BF_LO((q).w); acc[7] += BF_HI((q).w); \
    } while (0)

// ---------------------------------------------------------------- partition (single dispatch)
__global__ __launch_bounds__(256) void k_partition(const int* __restrict__ src,
                                                   const int* __restrict__ dst, int E,
                                                   int* __restrict__ bfill,
                                                   unsigned* __restrict__ packed, int B) {
    __shared__ int cnt[512];
    __shared__ int off[512];
    int t = threadIdx.x;
    for (int b = t; b < 512; b += 256) cnt[b] = 0;
    __syncthreads();
    int base = blockIdx.x * PEB;
#pragma unroll
    for (int i = 0; i < PEB / 256; ++i) {
        int e = base + i * 256 + t;
        if (e < E) atomicAdd(&cnt[dst[e] >> BSHIFT], 1);
    }
    __syncthreads();
    for (int b = t; b < B; b += 256) {
        int c = cnt[b];
        int o = c ? atomicAdd(&bfill[b], c) : 0;
        off[b] = (b << CAPSHIFT) + o;
    }
    __syncthreads();
#pragma unroll
    for (int i = 0; i < PEB / 256; ++i) {
        int e = base + i * 256 + t;
        if (e < E) {
            int d = dst[e];
            int s = src[e];
            int slot = atomicAdd(&off[d >> BSHIFT], 1);
            packed[slot] = ((unsigned)s << BSHIFT) | (unsigned)(d & BMASK);
        }
    }
}

// ---------------------------------------------------------------- per-bucket CSR build
__global__ __launch_bounds__(256) void k_csrfill(const unsigned* __restrict__ packed,
                                                 const int* __restrict__ bfill,
                                                 int* __restrict__ colidx,
                                                 uint2* __restrict__ rowptr2,
                                                 float* __restrict__ dinv,
                                                 int N, int B) {
    __shared__ int ldeg[256];
    __shared__ int lscan[256];
    __shared__ int sexc[256];
    __shared__ int lfill[256];
    int t = threadIdx.x, bkt = blockIdx.x;
    int base = bkt << CAPSHIFT;
    int end  = base + bfill[bkt];
    ldeg[t] = 0;
    __syncthreads();
    for (int e = base + t; e < end; e += 256)
        atomicAdd(&ldeg[packed[e] & BMASK], 1);
    __syncthreads();
    int v = ldeg[t];
    lscan[t] = v;
    __syncthreads();
    for (int off = 1; off < 256; off <<= 1) {
        int x = (t >= off) ? lscan[t - off] : 0;
        __syncthreads();
        lscan[t] += x;
        __syncthreads();
    }
    int exc = lscan[t] - v;
    sexc[t] = exc;
    lfill[t] = 0;
    int node = (bkt << BSHIFT) + t;
    if (node < N) {
        rowptr2[node] = make_uint2((unsigned)(base + exc), (unsigned)(base + exc + v));
        dinv[node] = rsqrtf((float)v + 1.0f);
    }
    __syncthreads();
    for (int e = base + t; e < end; e += 256) {
        unsigned w = packed[e];
        int ld = w & BMASK;
        int pos = base + sexc[ld] + atomicAdd(&lfill[ld], 1);
        colidx[pos] = (int)(w >> BSHIFT);
    }
}

// ---------------------------------------------------------------- GEMM1: g1b = bf16((x @ W1) * dinv)
__global__ __launch_bounds__(256) void k_gemm1(const float* __restrict__ x,
                                               const float* __restrict__ W,
                                               const float* __restrict__ dinv,
                                               unsigned* __restrict__ g1b, int N) {
    __shared__ float xs[64 * 36];
    __shared__ float ws[32 * 64];
    int t = threadIdx.x;
    int row0 = blockIdx.x * 64;
    int tx = t & 15;
    int ty = t >> 4;
    int sr = t >> 3, sc = t & 7;

    float acc[4][4] = {};
    for (int kt = 0; kt < 4; ++kt) {
        const float4* W4 = (const float4*)(W + kt * 32 * HID_DIM);
        float4* ws4 = (float4*)ws;
        ws4[t] = W4[t];
        ws4[t + 256] = W4[t + 256];
#pragma unroll
        for (int half = 0; half < 2; ++half) {
            int r = sr + half * 32;
            int row = row0 + r;
            float4 val = make_float4(0.f, 0.f, 0.f, 0.f);
            if (row < N)
                val = *(const float4*)&x[(size_t)row * IN_DIM + kt * 32 + sc * 4];
            *(float4*)&xs[r * 36 + sc * 4] = val;
        }
        __syncthreads();
#pragma unroll
        for (int k = 0; k < 32; k += 4) {
            float a[4][4], b[4][4];
#pragma unroll
            for (int i = 0; i < 4; ++i)
                *(float4*)a[i] = *(const float4*)&xs[(ty * 4 + i) * 36 + k];
#pragma unroll
            for (int kk = 0; kk < 4; ++kk)
                *(float4*)b[kk] = *(const float4*)&ws[(k + kk) * HID_DIM + tx * 4];
#pragma unroll
            for (int i = 0; i < 4; ++i)
#pragma unroll
                for (int kk = 0; kk < 4; ++kk)
#pragma unroll
                    for (int j = 0; j < 4; ++j)
                        acc[i][j] += a[i][kk] * b[kk][j];
        }
        __syncthreads();
    }
#pragma unroll
    for (int i = 0; i < 4; ++i) {
        int row = row0 + ty * 4 + i;
        if (row < N) {
            float dv = dinv[row];
            uint2 u;
            u.x = pack_bf16x2(acc[i][0] * dv, acc[i][1] * dv);
            u.y = pack_bf16x2(acc[i][2] * dv, acc[i][3] * dv);
            *(uint2*)&g1b[(size_t)row * 32 + tx * 2] = u;
        }
    }
}

// ---------------------------------------------------------------- agg layer 1
// 128 threads = 2 waves; node per 32-lane half (2 nodes/wave).
// hl = lane&31: grp = hl>>3 (0..3), fp = hl&7. uint4 loads, 8 lanes/row.
// Loop step 8: 2 loads -> 8 edges in flight per node (16/wave).
// Reduce: shfl_xor 8,16 (stays within the 32-lane half).
__global__ __launch_bounds__(128) void k_agg1(const unsigned* __restrict__ g1,
                                              const uint2* __restrict__ rowptr2,
                                              const int* __restrict__ colidx,
                                              const float* __restrict__ dinv,
                                              const float* __restrict__ b1,
                                              unsigned* __restrict__ t1b, int N) {
    int t = threadIdx.x;
    int lane = t & 63;
    int h = lane >> 5, hl = lane & 31;
    int grp = hl >> 3, fp = hl & 7;
    int dd = blockIdx.x * 4 + (t >> 6) * 2 + h;
    bool live = dd < N;
    int d = live ? dd : N - 1;

    uint2 be = rowptr2[d];
    v2f a01 = {0.f, 0.f}, a23 = {0.f, 0.f}, a45 = {0.f, 0.f}, a67 = {0.f, 0.f};
#define ACC8V(q)                                   \
    do {                                           \
        a01 += bfpair((q).x); a23 += bfpair((q).y);\
        a45 += bfpair((q).z); a67 += bfpair((q).w);\
    } while (0)
    int e = (int)be.x, end = (int)be.y;
    for (; e + 8 <= end; e += 8) {
        int s0 = colidx[e + grp];
        int s1 = colidx[e + 4 + grp];
        uint4 q0 = *(const uint4*)&g1[(size_t)s0 * 32 + fp * 4];
        uint4 q1 = *(const uint4*)&g1[(size_t)s1 * 32 + fp * 4];
        ACC8V(q0);
        ACC8V(q1);
    }
    for (; e + 4 <= end; e += 4) {
        int s = colidx[e + grp];
        uint4 q = *(const uint4*)&g1[(size_t)s * 32 + fp * 4];
        ACC8V(q);
    }
    if (e < end) {  // 1..3 edges left
        int cnt = end - e;
        int s = colidx[(grp < cnt) ? e + grp : e];
        uint4 q = *(const uint4*)&g1[(size_t)s * 32 + fp * 4];
        if (grp < cnt) ACC8V(q);
    }
#undef ACC8V
    float acc[8] = {a01.x, a01.y, a23.x, a23.y, a45.x, a45.y, a67.x, a67.y};
#pragma unroll
    for (int i = 0; i < 8; ++i) {
        acc[i] += __shfl_xor(acc[i], 8);
        acc[i] += __shfl_xor(acc[i], 16);
    }

    // self-loop + scale + bias + relu (per half)
    uint4 sq = *(const uint4*)&g1[(size_t)d * 32 + fp * 4];
    ACC8(sq);
    float dv = dinv[d];
    float4 bb0 = ((const float4*)b1)[fp * 2];
    float4 bb1 = ((const float4*)b1)[fp * 2 + 1];
    float v0 = fmaxf(dv * acc[0] + bb0.x, 0.f);
    float v1 = fmaxf(dv * acc[1] + bb0.y, 0.f);
    float v2 = fmaxf(dv * acc[2] + bb0.z, 0.f);
    float v3 = fmaxf(dv * acc[3] + bb0.w, 0.f);
    float v4 = fmaxf(dv * acc[4] + bb1.x, 0.f);
    float v5 = fmaxf(dv * acc[5] + bb1.y, 0.f);
    float v6 = fmaxf(dv * acc[6] + bb1.z, 0.f);
    float v7 = fmaxf(dv * acc[7] + bb1.w, 0.f);
    if (live && grp == 0) {
        uint4 u;
        u.x = pack_bf16x2(v0, v1);
        u.y = pack_bf16x2(v2, v3);
        u.z = pack_bf16x2(v4, v5);
        u.w = pack_bf16x2(v6, v7);
        *(uint4*)&t1b[(size_t)dd * 32 + fp * 4] = u;
    }
}

// ---------------------------------------------------------------- GEMM2: g2b = bf16((t1b @ W2) * dinv)
__global__ __launch_bounds__(256) void k_gemm2b(const unsigned* __restrict__ t1b,
                                                const float* __restrict__ W2,
                                                const float* __restrict__ dinv,
                                                unsigned* __restrict__ g2b, int N) {
    __shared__ unsigned t1s[64 * 33];       // bf16x2, row stride 33 (+1 pad)
    __shared__ float W2s[HID_DIM * OUT_DIM];
    int t = threadIdx.x;
    int row0 = blockIdx.x * 64;

    const float4* W24 = (const float4*)W2;  // 512 float4
    float4* W2s4 = (float4*)W2s;
#pragma unroll
    for (int i = 0; i < 2; ++i) W2s4[t + 256 * i] = W24[t + 256 * i];
#pragma unroll
    for (int i = 0; i < 8; ++i) {           // 2048 uints
        int l = t + 256 * i;
        int r = l >> 5, c = l & 31;
        int row = row0 + r;
        unsigned val = 0;
        if (row < N) val = t1b[(size_t)row * 32 + c];
        t1s[r * 33 + c] = val;
    }
    __syncthreads();

    int r = t >> 2, q = t & 3;
    float acc[8] = {};
    const unsigned* trow = &t1s[r * 33];
    const float* wbase = &W2s[q * 8];
#pragma unroll
    for (int kp = 0; kp < 32; ++kp) {
        unsigned u = trow[kp];
        float a0 = BF_LO(u), a1 = BF_HI(u);
        float4 w00 = *(const float4*)&wbase[(2 * kp) * OUT_DIM];
        float4 w01 = *(const float4*)&wbase[(2 * kp) * OUT_DIM + 4];
        float4 w10 = *(const float4*)&wbase[(2 * kp + 1) * OUT_DIM];
        float4 w11 = *(const float4*)&wbase[(2 * kp + 1) * OUT_DIM + 4];
        acc[0] += a0 * w00.x + a1 * w10.x;
        acc[1] += a0 * w00.y + a1 * w10.y;
        acc[2] += a0 * w00.z + a1 * w10.z;
        acc[3] += a0 * w00.w + a1 * w10.w;
        acc[4] += a0 * w01.x + a1 * w11.x;
        acc[5] += a0 * w01.y + a1 * w11.y;
        acc[6] += a0 * w01.z + a1 * w11.z;
        acc[7] += a0 * w01.w + a1 * w11.w;
    }
    int row = row0 + r;
    if (row < N) {
        float dv = dinv[row];
        uint4 u;
        u.x = pack_bf16x2(acc[0] * dv, acc[1] * dv);
        u.y = pack_bf16x2(acc[2] * dv, acc[3] * dv);
        u.z = pack_bf16x2(acc[4] * dv, acc[5] * dv);
        u.w = pack_bf16x2(acc[6] * dv, acc[7] * dv);
        *(uint4*)&g2b[(size_t)row * 16 + q * 4] = u;
    }
}

// ---------------------------------------------------------------- agg layer 2
// 128 threads = 2 waves; node per 16-lane quarter (4 nodes/wave).
// ql = lane&15: grp = ql>>2 (0..3), fp = ql&3. uint4 loads, 4 lanes/row.
// Loop step 8: 2 loads -> 8 edges in flight per node (32/wave).
// Reduce: shfl_xor 4,8 (stays within the 16-lane quarter).
__global__ __launch_bounds__(128) void k_agg2(const unsigned* __restrict__ g2,
                                              const uint2* __restrict__ rowptr2,
                                              const int* __restrict__ colidx,
                                              const float* __restrict__ dinv,
                                              const float* __restrict__ b2,
                                              float* __restrict__ out, int N) {
    int t = threadIdx.x;
    int lane = t & 63;
    int qd = lane >> 4, ql = lane & 15;
    int grp = ql >> 2, fp = ql & 3;
    int dd = blockIdx.x * 8 + (t >> 6) * 4 + qd;
    bool live = dd < N;
    int d = live ? dd : N - 1;

    uint2 be = rowptr2[d];
    v2f a01 = {0.f, 0.f}, a23 = {0.f, 0.f}, a45 = {0.f, 0.f}, a67 = {0.f, 0.f};
#define ACC8V(q)                                   \
    do {                                           \
        a01 += bfpair((q).x); a23 += bfpair((q).y);\
        a45 += bfpair((q).z); a67 += bfpair((q).w);\
    } while (0)
    int e = (int)be.x, end = (int)be.y;
    for (; e + 8 <= end; e += 8) {
        int s0 = colidx[e + grp];
        int s1 = colidx[e + 4 + grp];
        uint4 q0 = *(const uint4*)&g2[(size_t)s0 * 16 + fp * 4];
        uint4 q1 = *(const uint4*)&g2[(size_t)s1 * 16 + fp * 4];
        ACC8V(q0);
        ACC8V(q1);
    }
    for (; e + 4 <= end; e += 4) {
        int s = colidx[e + grp];
        uint4 q = *(const uint4*)&g2[(size_t)s * 16 + fp * 4];
        ACC8V(q);
    }
    if (e < end) {  // 1..3 edges left
        int cnt = end - e;
        int s = colidx[(grp < cnt) ? e + grp : e];
        uint4 q = *(const uint4*)&g2[(size_t)s * 16 + fp * 4];
        if (grp < cnt) ACC8V(q);
    }
#undef ACC8V
    float acc[8] = {a01.x, a01.y, a23.x, a23.y, a45.x, a45.y, a67.x, a67.y};
#pragma unroll
    for (int i = 0; i < 8; ++i) {
        acc[i] += __shfl_xor(acc[i], 4);
        acc[i] += __shfl_xor(acc[i], 8);
    }
    // self-loop + epilogue (per quarter)
    uint4 sq = *(const uint4*)&g2[(size_t)d * 16 + fp * 4];
    ACC8(sq);
    float dv = dinv[d];
    float4 bb0 = ((const float4*)b2)[fp * 2];
    float4 bb1 = ((const float4*)b2)[fp * 2 + 1];
    if (live && grp == 0) {
        float4 r0, r1;
        r0.x = dv * acc[0] + bb0.x; r0.y = dv * acc[1] + bb0.y;
        r0.z = dv * acc[2] + bb0.z; r0.w = dv * acc[3] + bb0.w;
        r1.x = dv * acc[4] + bb1.x; r1.y = dv * acc[5] + bb1.y;
        r1.z = dv * acc[6] + bb1.z; r1.w = dv * acc[7] + bb1.w;
        *(float4*)&out[(size_t)dd * OUT_DIM + fp * 8] = r0;
        *(float4*)&out[(size_t)dd * OUT_DIM + fp * 8 + 4] = r1;
    }
}

// ---------------------------------------------------------------- launch
extern "C" void kernel_launch(void* const* d_in, const int* in_sizes, int n_in,
                              void* d_out, int out_size, void* d_ws, size_t ws_size,
                              hipStream_t stream) {
    const float* x  = (const float*)d_in[0];
    const int*   ei = (const int*)d_in[1];
    const float* W1 = (const float*)d_in[2];
    const float* b1 = (const float*)d_in[3];
    const float* W2 = (const float*)d_in[4];
    const float* b2 = (const float*)d_in[5];
    float* out = (float*)d_out;

    const int N = in_sizes[0] / IN_DIM;
    const int E = in_sizes[1] / 2;
    const int* src = ei;
    const int* dst = ei + E;

    const int B   = (N + BSIZE - 1) / BSIZE;          // buckets
    const int nPB = (E + PEB - 1) / PEB;              // partition blocks
    const size_t SLOTS = (size_t)B << CAPSHIFT;       // segmented edge slots

    char* p = (char*)d_ws;
    auto alloc = [&](size_t bytes) -> void* {
        void* r = (void*)p;
        p += (bytes + 255) & ~(size_t)255;
        return r;
    };
    int*      bfill   = (int*)alloc((size_t)B * 4);
    unsigned* packed  = (unsigned*)alloc(SLOTS * 4);
    int*      colidx  = (int*)alloc(SLOTS * 4);
    uint2*    rowptr2 = (uint2*)alloc((size_t)N * 8);
    float*    dinv    = (float*)alloc((size_t)N * 4);
    unsigned* g1b     = (unsigned*)alloc((size_t)N * 32 * 4);  // bf16x2 x 32/row
    unsigned* t1b     = (unsigned*)alloc((size_t)N * 32 * 4);  // bf16x2 x 32/row
    unsigned* g2b     = (unsigned*)alloc((size_t)N * 16 * 4);  // bf16x2 x 16/row

    hipMemsetAsync(bfill, 0, (size_t)B * 4, stream);
    k_partition<<<nPB, 256, 0, stream>>>(src, dst, E, bfill, packed, B);
    k_csrfill<<<B, 256, 0, stream>>>(packed, bfill, colidx, rowptr2, dinv, N, B);

    k_gemm1<<<(N + 63) / 64, 256, 0, stream>>>(x, W1, dinv, g1b, N);
    k_agg1<<<(N + 3) / 4, 128, 0, stream>>>(g1b, rowptr2, colidx, dinv, b1, t1b, N);
    k_gemm2b<<<(N + 63) / 64, 256, 0, stream>>>(t1b, W2, dinv, g2b, N);
    k_agg2<<<(N + 7) / 8, 128, 0, stream>>>(g2b, rowptr2, colidx, dinv, b2, out, N);
}